// Round 2
// baseline (4263.062 us; speedup 1.0000x reference)
//
#include <hip/hip_runtime.h>
#include <math.h>

#define N_NODES 25600
#define F_IN    128
#define H_GNN   256
#define D_MLP   512
#define E_EDGE  409600
#define B_GR    256
#define NPG_    100
#define R_LSTM  512
#define V_OUT   32000

// ---------------------------------------------------------------------------
// Generic f32 tiled GEMM: C[M,N] = A[M,K] @ B (+bias). TRANSB: B is N x K.
// SplitK via blockIdx.z (atomicAdd into pre-zeroed C).
// ---------------------------------------------------------------------------
template<bool TRANSB>
__global__ __launch_bounds__(256)
void gemm_tile(const float* __restrict__ A, const float* __restrict__ B,
               float* __restrict__ C, const float* __restrict__ bias,
               int M, int N, int K, int lda, int ldb, int ldc, int kChunk)
{
    __shared__ float As[16][68];
    __shared__ float Bs[16][68];
    const int tid = threadIdx.x;
    const int n0 = blockIdx.x * 64;
    const int m0 = blockIdx.y * 64;
    const int z  = blockIdx.z;
    const int k0 = z * kChunk;
    const int k1 = min(K, k0 + kChunk);
    const int ty = tid >> 4, tx = tid & 15;
    float acc[4][4] = {};

    for (int kb = k0; kb < k1; kb += 16) {
        {   // A tile 64x16 -> As[k][m]
            const int r = tid >> 4, c = tid & 15;
            #pragma unroll
            for (int i = 0; i < 4; ++i) {
                int rr = r + i * 16;
                int gm = m0 + rr, gk = kb + c;
                As[c][rr] = (gm < M && gk < k1) ? A[gm * lda + gk] : 0.f;
            }
        }
        if (!TRANSB) {  // B tile 16x64 -> Bs[k][n]
            const int r = tid >> 6, c = tid & 63;
            #pragma unroll
            for (int i = 0; i < 4; ++i) {
                int rr = r + i * 4;
                int gk = kb + rr, gn = n0 + c;
                Bs[rr][c] = (gk < k1 && gn < N) ? B[gk * ldb + gn] : 0.f;
            }
        } else {        // B is N x K row-major
            const int r = tid & 15, c = tid >> 4;
            #pragma unroll
            for (int i = 0; i < 4; ++i) {
                int cc = c + i * 16;
                int gk = kb + r, gn = n0 + cc;
                Bs[r][cc] = (gk < k1 && gn < N) ? B[gn * ldb + gk] : 0.f;
            }
        }
        __syncthreads();
        #pragma unroll
        for (int kk = 0; kk < 16; ++kk) {
            float a[4], b[4];
            #pragma unroll
            for (int i = 0; i < 4; ++i) a[i] = As[kk][ty * 4 + i];
            #pragma unroll
            for (int j = 0; j < 4; ++j) b[j] = Bs[kk][tx * 4 + j];
            #pragma unroll
            for (int i = 0; i < 4; ++i)
                #pragma unroll
                for (int j = 0; j < 4; ++j)
                    acc[i][j] = fmaf(a[i], b[j], acc[i][j]);
        }
        __syncthreads();
    }

    const bool split = (gridDim.z > 1);
    #pragma unroll
    for (int i = 0; i < 4; ++i) {
        int gm = m0 + ty * 4 + i;
        if (gm >= M) continue;
        #pragma unroll
        for (int j = 0; j < 4; ++j) {
            int gn = n0 + tx * 4 + j;
            if (gn >= N) continue;
            float v = acc[i][j];
            if (bias != nullptr && z == 0) v += bias[gn];
            if (split) atomicAdd(&C[gm * ldc + gn], v);
            else       C[gm * ldc + gn] = v;
        }
    }
}

// ---------------------------------------------------------------------------
// small utility kernels
// ---------------------------------------------------------------------------
__global__ void zero_f32(float* p, long n) {
    for (long i = (long)blockIdx.x * blockDim.x + threadIdx.x; i < n;
         i += (long)gridDim.x * blockDim.x) p[i] = 0.f;
}
__global__ void zero_i32(int* p, long n) {
    for (long i = (long)blockIdx.x * blockDim.x + threadIdx.x; i < n;
         i += (long)gridDim.x * blockDim.x) p[i] = 0;
}
__global__ void addvec_kernel(const float* a, const float* b, float* o, int n) {
    int i = blockIdx.x * blockDim.x + threadIdx.x;
    if (i < n) o[i] = a[i] + b[i];
}

// CSR build
__global__ void hist_kernel(const int* __restrict__ key, int* counts, int E) {
    int i = blockIdx.x * blockDim.x + threadIdx.x;
    if (i < E) atomicAdd(&counts[key[i]], 1);
}
__global__ __launch_bounds__(256)
void scan_kernel(const int* __restrict__ counts, int* rowptr, int* cursor, int n) {
    __shared__ int buf[256];
    __shared__ int carry_s;
    const int tid = threadIdx.x;
    if (tid == 0) carry_s = 0;
    __syncthreads();
    const int nch = (n + 255) / 256;
    for (int ch = 0; ch < nch; ++ch) {
        int i = ch * 256 + tid;
        int v = (i < n) ? counts[i] : 0;
        buf[tid] = v;
        __syncthreads();
        for (int off = 1; off < 256; off <<= 1) {
            int add = (tid >= off) ? buf[tid - off] : 0;
            __syncthreads();
            buf[tid] += add;
            __syncthreads();
        }
        int incl = buf[tid];
        int base = carry_s;
        if (i < n) {
            rowptr[i + 1] = base + incl;
            cursor[i]     = base + incl - v;
        }
        if (ch == 0 && tid == 0) rowptr[0] = 0;
        __syncthreads();
        if (tid == 255) carry_s = base + incl;
        __syncthreads();
    }
}
__global__ void scatter_kernel(const int* __restrict__ key, const int* __restrict__ val,
                               int* cursor, int* sorted, int E) {
    int i = blockIdx.x * blockDim.x + threadIdx.x;
    if (i < E) {
        int pos = atomicAdd(&cursor[key[i]], 1);
        sorted[pos] = val[i];
    }
}
// per-node aggregation + conv epilogue: xc[n, off+c] = relu(xr[n,c] + sum xn[src,c])
__global__ __launch_bounds__(256)
void agg_conv_kernel(const float* __restrict__ xr, const float* __restrict__ xn,
                     const int* __restrict__ rowptr, const int* __restrict__ sorted,
                     float* __restrict__ xc, int halfOff) {
    const int n = blockIdx.x, tid = threadIdx.x;
    float acc = xr[n * H_GNN + tid];
    const int s = rowptr[n], e = rowptr[n + 1];
    for (int t = s; t < e; ++t) {
        int src = sorted[t];
        acc += xn[src * H_GNN + tid];
    }
    xc[n * D_MLP + halfOff + tid] = fmaxf(acc, 0.f);
}

// column stats over 25600 rows (512 cols)
__global__ __launch_bounds__(512)
void colstat_kernel(const float* __restrict__ h1, float* colsum, float* colsq) {
    const int c = threadIdx.x;
    const int r0 = blockIdx.x * 128;
    float s = 0.f, s2 = 0.f;
    for (int r = 0; r < 128; ++r) {
        float v = h1[(r0 + r) * D_MLP + c];
        s += v; s2 += v * v;
    }
    atomicAdd(&colsum[c], s);
    atomicAdd(&colsq[c], s2);
}
__global__ void finalize_stats(const float* colsum, const float* colsq,
                               const float* gamma, const float* beta,
                               float* scalev, float* shiftv) {
    int c = threadIdx.x;
    float m  = colsum[c] * (1.f / N_NODES);
    float vr = colsq[c] * (1.f / N_NODES) - m * m;
    float g  = gamma[c] * rsqrtf(vr + 1e-5f);
    scalev[c] = g;
    shiftv[c] = beta[c] - m * g;
}
__global__ void norm_relu(float* h, const float* __restrict__ sc,
                          const float* __restrict__ sh, long n) {
    for (long i = (long)blockIdx.x * blockDim.x + threadIdx.x; i < n;
         i += (long)gridDim.x * blockDim.x) {
        int c = (int)(i & 511);
        h[i] = fmaxf(fmaf(h[i], sc[c], sh[c]), 0.f);
    }
}
__global__ __launch_bounds__(512)
void pool_kernel(const float* __restrict__ hrelu, float* P) {
    const int b = blockIdx.x, c = threadIdx.x;
    float s = 0.f;
    for (int i = 0; i < NPG_; ++i) s += hrelu[(b * NPG_ + i) * D_MLP + c];
    P[b * D_MLP + c] = s * (1.f / NPG_);
}
// sW[l,p] = dot(c0[l,:], W_alm[p, 0:512])
__global__ void sw_kernel(const float* __restrict__ c0, const float* __restrict__ W_alm,
                          float* sW) {
    int i = blockIdx.x * blockDim.x + threadIdx.x;
    if (i < 2 * NPG_) {
        int l = i / NPG_, p = i % NPG_;
        float s = 0.f;
        for (int k = 0; k < R_LSTM; ++k) s += c0[l * R_LSTM + k] * W_alm[p * 51712 + k];
        sW[l * NPG_ + p] = s;
    }
}
__global__ __launch_bounds__(128)
void alpha_kernel(const float* __restrict__ sW, const float* __restrict__ hW,
                  const float* __restrict__ b_alm, float* __restrict__ alpha) {
    const int lb = blockIdx.x;          // l*256 + b
    const int l = lb >> 8, b = lb & 255;
    const int p = threadIdx.x;
    __shared__ float red[128];
    float v = 0.f;
    if (p < NPG_) v = sW[l * NPG_ + p] + hW[b * NPG_ + p] + b_alm[p];
    red[p] = v;
    __syncthreads();
    for (int s = 64; s > 0; s >>= 1) {
        if (p < s) red[p] += red[p + s];
        __syncthreads();
    }
    float inv = 1.f / red[0];
    if (p < NPG_) alpha[lb * NPG_ + p] = v * inv;
}
__global__ __launch_bounds__(512)
void newc_kernel(const float* __restrict__ alpha, const float* __restrict__ xc,
                 float* new_c) {
    const int l = blockIdx.y, chunk = blockIdx.x, c = threadIdx.x;
    const int r0 = chunk * 800;
    float acc = 0.f;
    for (int r = r0; r < r0 + 800; ++r)
        acc += alpha[l * N_NODES + r] * xc[r * D_MLP + c];
    atomicAdd(&new_c[l * D_MLP + c], acc);
}
__global__ void lstm_init_kernel(const float* __restrict__ h0, float* h0buf, float* h1buf,
                                 int* cnt0, int* cnt1) {
    int i = blockIdx.x * blockDim.x + threadIdx.x;
    if (i < 512) { h0buf[i] = h0[i]; h1buf[i] = h0[512 + i]; }
    if (i < 257) { cnt0[i] = 0; cnt1[i] = 0; }
}

// ---------------------------------------------------------------------------
// Persistent 2-layer LSTM, 256 sequential steps, batch 1.
// 64 blocks x 256 threads: blocks 0..31 = layer0, 32..63 = layer1.
// Each block owns 16 h/c indices (4 gates x 16 = 64 weight rows, 4-lane teams).
// Cross-block sync via agent-scope atomic counters per step; layers pipelined.
// Spins are BOUNDED (~15 ms each) so a sync failure gives a wrong answer,
// never a GPU hang.
// ---------------------------------------------------------------------------
#define LG0 32
#define LG1 32
#define SPIN_MAX 500000
__device__ __forceinline__ float sigf(float x) { return 1.f / (1.f + expf(-x)); }

__device__ __forceinline__ void wait_ge(int* p, int val) {
    int guard = 0;
    while (__hip_atomic_load(p, __ATOMIC_ACQUIRE, __HIP_MEMORY_SCOPE_AGENT) < val
           && guard < SPIN_MAX) {
        ++guard;
        __builtin_amdgcn_s_sleep(1);
    }
}

__global__ __launch_bounds__(256)
void lstm_kernel(const float* __restrict__ inp0, const float* __restrict__ Whh0,
                 const float* __restrict__ Wih1, const float* __restrict__ Whh1,
                 const float* __restrict__ b1s, const float* __restrict__ new_c,
                 float* h0buf, float* h1buf, int* cnt0, int* cnt1)
{
    const int tid = threadIdx.x;
    const int blk = blockIdx.x;
    __shared__ float xv_s[1024];
    __shared__ float gate_s[64];
    __shared__ float c_s[16];
    const int r = tid >> 2;          // 0..63 gate-row
    const int q = tid & 3;           // k-quarter
    if (blk < LG0) {
        const int base = blk * 16;
        const int gate = r >> 4;
        const int hidx = base + (r & 15);
        const float* wrow = Whh0 + (gate * 512 + hidx) * 512 + q * 128;
        if (tid < 16) c_s[tid] = new_c[base + tid];
        __syncthreads();
        for (int t = 0; t < 256; ++t) {
            if (t > 0 && tid == 0) wait_ge(&cnt0[t], LG0);
            __syncthreads();
            #pragma unroll
            for (int i = 0; i < 2; ++i) {
                int idx = tid + i * 256;
                xv_s[idx] = __hip_atomic_load(&h0buf[t * 512 + idx], __ATOMIC_RELAXED, __HIP_MEMORY_SCOPE_AGENT);
            }
            __syncthreads();
            float acc = 0.f;
            const float* hv = xv_s + q * 128;
            #pragma unroll 8
            for (int k = 0; k < 128; ++k) acc = fmaf(wrow[k], hv[k], acc);
            acc += __shfl_xor(acc, 1);
            acc += __shfl_xor(acc, 2);
            if (q == 0) gate_s[r] = acc;
            __syncthreads();
            if (tid < 16) {
                const float* ip = inp0 + t * 2048;
                float ig = sigf(gate_s[tid]      + ip[base + tid]);
                float fg = sigf(gate_s[16 + tid] + ip[512 + base + tid]);
                float gg = tanhf(gate_s[32 + tid] + ip[1024 + base + tid]);
                float og = sigf(gate_s[48 + tid] + ip[1536 + base + tid]);
                float c = fg * c_s[tid] + ig * gg;
                c_s[tid] = c;
                float h = og * tanhf(c);
                __hip_atomic_store(&h0buf[(t + 1) * 512 + base + tid], h, __ATOMIC_RELAXED, __HIP_MEMORY_SCOPE_AGENT);
            }
            __syncthreads();
            if (tid == 0)
                __hip_atomic_fetch_add(&cnt0[t + 1], 1, __ATOMIC_RELEASE, __HIP_MEMORY_SCOPE_AGENT);
        }
    } else {
        const int base = (blk - LG0) * 16;
        const int gate = r >> 4;
        const int hidx = base + (r & 15);
        const float* wi = Wih1 + (gate * 512 + hidx) * 512 + q * 128;
        const float* wh = Whh1 + (gate * 512 + hidx) * 512 + q * 128;
        if (tid < 16) c_s[tid] = new_c[512 + base + tid];
        __syncthreads();
        for (int t = 0; t < 256; ++t) {
            if (tid == 0) {
                wait_ge(&cnt0[t + 1], LG0);
                if (t > 0) wait_ge(&cnt1[t], LG1);
            }
            __syncthreads();
            #pragma unroll
            for (int i = 0; i < 2; ++i) {
                int idx = tid + i * 256;
                xv_s[idx]       = __hip_atomic_load(&h0buf[(t + 1) * 512 + idx], __ATOMIC_RELAXED, __HIP_MEMORY_SCOPE_AGENT);
                xv_s[512 + idx] = __hip_atomic_load(&h1buf[t * 512 + idx],       __ATOMIC_RELAXED, __HIP_MEMORY_SCOPE_AGENT);
            }
            __syncthreads();
            float acc = 0.f;
            const float* xv = xv_s + q * 128;
            #pragma unroll 8
            for (int k = 0; k < 128; ++k) acc = fmaf(wi[k], xv[k], acc);
            const float* hv = xv_s + 512 + q * 128;
            #pragma unroll 8
            for (int k = 0; k < 128; ++k) acc = fmaf(wh[k], hv[k], acc);
            acc += __shfl_xor(acc, 1);
            acc += __shfl_xor(acc, 2);
            if (q == 0) gate_s[r] = acc;
            __syncthreads();
            if (tid < 16) {
                float ig = sigf(gate_s[tid]      + b1s[base + tid]);
                float fg = sigf(gate_s[16 + tid] + b1s[512 + base + tid]);
                float gg = tanhf(gate_s[32 + tid] + b1s[1024 + base + tid]);
                float og = sigf(gate_s[48 + tid] + b1s[1536 + base + tid]);
                float c = fg * c_s[tid] + ig * gg;
                c_s[tid] = c;
                float h = og * tanhf(c);
                __hip_atomic_store(&h1buf[(t + 1) * 512 + base + tid], h, __ATOMIC_RELAXED, __HIP_MEMORY_SCOPE_AGENT);
            }
            __syncthreads();
            if (tid == 0)
                __hip_atomic_fetch_add(&cnt1[t + 1], 1, __ATOMIC_RELEASE, __HIP_MEMORY_SCOPE_AGENT);
        }
    }
}

// ---------------------------------------------------------------------------
extern "C" void kernel_launch(void* const* d_in, const int* in_sizes, int n_in,
                              void* d_out, int out_size, void* d_ws, size_t ws_size,
                              hipStream_t stream)
{
    const float* x      = (const float*)d_in[0];
    const int*   ei     = (const int*)d_in[1];
    const float* h0     = (const float*)d_in[4];
    const float* c0     = (const float*)d_in[5];
    const float* W_gnn  = (const float*)d_in[6];
    const float* W_root = (const float*)d_in[7];
    const float* W_nbr  = (const float*)d_in[8];
    const float* b_conv = (const float*)d_in[9];
    const float* W1     = (const float*)d_in[10];
    const float* b1     = (const float*)d_in[11];
    const float* gamma  = (const float*)d_in[12];
    const float* beta   = (const float*)d_in[13];
    const float* W2     = (const float*)d_in[14];
    const float* b2     = (const float*)d_in[15];
    const float* W_alm  = (const float*)d_in[16];
    const float* b_alm  = (const float*)d_in[17];
    const float* Wih0   = (const float*)d_in[18];
    const float* Whh0   = (const float*)d_in[19];
    const float* bih0   = (const float*)d_in[20];
    const float* bhh0   = (const float*)d_in[21];
    const float* Wih1   = (const float*)d_in[22];
    const float* Whh1   = (const float*)d_in[23];
    const float* bih1   = (const float*)d_in[24];
    const float* bhh1   = (const float*)d_in[25];
    const float* W_fc   = (const float*)d_in[26];
    const float* b_fc   = (const float*)d_in[27];
    float* out = (float*)d_out;
    float* ws  = (float*)d_ws;

    const int* ei0 = ei;            // src
    const int* ei1 = ei + E_EDGE;   // dst

    // ---- workspace layout (floats) ----
    float* xr = ws;                       // 25600x256
    float* xn = ws + 6553600L;            // 25600x256
    float* xc = ws + 13107200L;           // 25600x512 (lives long)
    float* h1m = ws;                      // 25600x512, overlays xr+xn (both dead)
    long o = 26214400L;
    float* Wgr   = ws + o; o += 32768;    // 128x256
    float* Wgn   = ws + o; o += 32768;
    int*   counts= (int*)(ws + o); o += 25600;
    int*   rowptr= (int*)(ws + o); o += 25601;
    int*   cursor= (int*)(ws + o); o += 25600;
    int*   sorted= (int*)(ws + o); o += 409600;
    float* colsum= ws + o; o += 512;
    float* colsq = ws + o; o += 512;
    float* scalev= ws + o; o += 512;
    float* shiftv= ws + o; o += 512;
    float* P     = ws + o; o += 131072;   // 256x512
    float* x_g   = ws + o; o += 131072;   // 256x512
    float* hW    = ws + o; o += 25600;    // 256x100
    float* sW    = ws + o; o += 200;
    float* alphav= ws + o; o += 51200;    // 2x256x100
    float* newc  = ws + o; o += 1024;     // 2x512
    float* b0s   = ws + o; o += 2048;
    float* b1s   = ws + o; o += 2048;
    float* inp0  = ws + o; o += 524288;   // 256x2048
    float* h0st  = ws + o; o += 131584;   // 257x512
    float* h1st  = ws + o; o += 131584;
    int*   cnt0  = (int*)(ws + o); o += 257;
    int*   cnt1  = (int*)(ws + o); o += 257;

    // 1. fold W_gnn into conv weights: Wgr = W_gnn@W_root, Wgn = W_gnn@W_nbr
    gemm_tile<false><<<dim3(4, 2, 1), 256, 0, stream>>>(W_gnn, W_root, Wgr, nullptr,
        128, 256, 256, 256, 256, 256, 256);
    gemm_tile<false><<<dim3(4, 2, 1), 256, 0, stream>>>(W_gnn, W_nbr, Wgn, nullptr,
        128, 256, 256, 256, 256, 256, 256);
    // 2. xr = x@Wgr + b_conv ; xn = x@Wgn
    gemm_tile<false><<<dim3(4, 400, 1), 256, 0, stream>>>(x, Wgr, xr, b_conv,
        N_NODES, 256, 128, 128, 256, 256, 128);
    gemm_tile<false><<<dim3(4, 400, 1), 256, 0, stream>>>(x, Wgn, xn, nullptr,
        N_NODES, 256, 128, 128, 256, 256, 128);
    // 3. forward conv: CSR by dst, gather xn[src]
    zero_i32<<<dim3(100), 256, 0, stream>>>(counts, 25600);
    hist_kernel<<<dim3(1600), 256, 0, stream>>>(ei1, counts, E_EDGE);
    scan_kernel<<<dim3(1), 256, 0, stream>>>(counts, rowptr, cursor, 25600);
    scatter_kernel<<<dim3(1600), 256, 0, stream>>>(ei1, ei0, cursor, sorted, E_EDGE);
    agg_conv_kernel<<<dim3(25600), 256, 0, stream>>>(xr, xn, rowptr, sorted, xc, 0);
    // 4. backward conv: CSR by src, gather xn[dst]
    zero_i32<<<dim3(100), 256, 0, stream>>>(counts, 25600);
    hist_kernel<<<dim3(1600), 256, 0, stream>>>(ei0, counts, E_EDGE);
    scan_kernel<<<dim3(1), 256, 0, stream>>>(counts, rowptr, cursor, 25600);
    scatter_kernel<<<dim3(1600), 256, 0, stream>>>(ei0, ei1, cursor, sorted, E_EDGE);
    agg_conv_kernel<<<dim3(25600), 256, 0, stream>>>(xr, xn, rowptr, sorted, xc, 256);
    // 5. h1 = xc@W1 + b1  (into overlay region)
    gemm_tile<false><<<dim3(8, 400, 1), 256, 0, stream>>>(xc, W1, h1m, b1,
        N_NODES, 512, 512, 512, 512, 512, 512);
    // 6. per-column layernorm + relu (in place)
    zero_f32<<<dim3(4), 256, 0, stream>>>(colsum, 1024);
    colstat_kernel<<<dim3(200), 512, 0, stream>>>(h1m, colsum, colsq);
    finalize_stats<<<dim3(1), 512, 0, stream>>>(colsum, colsq, gamma, beta, scalev, shiftv);
    norm_relu<<<dim3(2048), 256, 0, stream>>>(h1m, scalev, shiftv, (long)N_NODES * 512);
    // 7. graph mean-pool, then x_g = P@W2 + b2 (pool-before-GEMM)
    pool_kernel<<<dim3(256), 512, 0, stream>>>(h1m, P);
    gemm_tile<false><<<dim3(8, 4, 1), 256, 0, stream>>>(P, W2, x_g, b2,
        256, 512, 512, 512, 512, 512, 512);
    // 8. hW = xc_flat(256x51200) @ Wh^T  (split-K)
    zero_f32<<<dim3(25), 256, 0, stream>>>(hW, 25600);
    gemm_tile<true><<<dim3(2, 4, 32), 256, 0, stream>>>(xc, W_alm + 512, hW, nullptr,
        256, 100, 51200, 51200, 51712, 100, 1600);
    // 9. alpha and new_c
    sw_kernel<<<dim3(1), 256, 0, stream>>>(c0, W_alm, sW);
    alpha_kernel<<<dim3(512), 128, 0, stream>>>(sW, hW, b_alm, alphav);
    zero_f32<<<dim3(1), 256, 0, stream>>>(newc, 1024);
    newc_kernel<<<dim3(32, 2), 512, 0, stream>>>(alphav, xc, newc);
    // 10. LSTM input projection (layer 0, all steps) + bias sums
    addvec_kernel<<<dim3(8), 256, 0, stream>>>(bih0, bhh0, b0s, 2048);
    addvec_kernel<<<dim3(8), 256, 0, stream>>>(bih1, bhh1, b1s, 2048);
    gemm_tile<true><<<dim3(32, 4, 1), 256, 0, stream>>>(x_g, Wih0, inp0, b0s,
        256, 2048, 512, 512, 512, 2048, 512);
    // 11. persistent 2-layer LSTM
    lstm_init_kernel<<<dim3(2), 512, 0, stream>>>(h0, h0st, h1st, cnt0, cnt1);
    lstm_kernel<<<dim3(64), 256, 0, stream>>>(inp0, Whh0, Wih1, Whh1, b1s, newc,
                                              h0st, h1st, cnt0, cnt1);
    // 12. preds = outs1 @ W_fc + b_fc
    gemm_tile<false><<<dim3(500, 4, 1), 256, 0, stream>>>(h1st + 512, W_fc, out, b_fc,
        256, V_OUT, 512, 512, V_OUT, V_OUT, 512);
}

// Round 3
// 2456.717 us; speedup vs baseline: 1.7353x; 1.7353x over previous
//
#include <hip/hip_runtime.h>
#include <math.h>

#define N_NODES 25600
#define F_IN    128
#define H_GNN   256
#define D_MLP   512
#define E_EDGE  409600
#define B_GR    256
#define NPG_    100
#define R_LSTM  512
#define V_OUT   32000

// ---------------------------------------------------------------------------
// Generic f32 tiled GEMM: C[M,N] = A[M,K] @ B (+bias). TRANSB: B is N x K.
// SplitK via blockIdx.z (atomicAdd into pre-zeroed C).
// ---------------------------------------------------------------------------
template<bool TRANSB>
__global__ __launch_bounds__(256)
void gemm_tile(const float* __restrict__ A, const float* __restrict__ B,
               float* __restrict__ C, const float* __restrict__ bias,
               int M, int N, int K, int lda, int ldb, int ldc, int kChunk)
{
    __shared__ float As[16][68];
    __shared__ float Bs[16][68];
    const int tid = threadIdx.x;
    const int n0 = blockIdx.x * 64;
    const int m0 = blockIdx.y * 64;
    const int z  = blockIdx.z;
    const int k0 = z * kChunk;
    const int k1 = min(K, k0 + kChunk);
    const int ty = tid >> 4, tx = tid & 15;
    float acc[4][4] = {};

    for (int kb = k0; kb < k1; kb += 16) {
        {   // A tile 64x16 -> As[k][m]
            const int r = tid >> 4, c = tid & 15;
            #pragma unroll
            for (int i = 0; i < 4; ++i) {
                int rr = r + i * 16;
                int gm = m0 + rr, gk = kb + c;
                As[c][rr] = (gm < M && gk < k1) ? A[gm * lda + gk] : 0.f;
            }
        }
        if (!TRANSB) {  // B tile 16x64 -> Bs[k][n]
            const int r = tid >> 6, c = tid & 63;
            #pragma unroll
            for (int i = 0; i < 4; ++i) {
                int rr = r + i * 4;
                int gk = kb + rr, gn = n0 + c;
                Bs[rr][c] = (gk < k1 && gn < N) ? B[gk * ldb + gn] : 0.f;
            }
        } else {        // B is N x K row-major
            const int r = tid & 15, c = tid >> 4;
            #pragma unroll
            for (int i = 0; i < 4; ++i) {
                int cc = c + i * 16;
                int gk = kb + r, gn = n0 + cc;
                Bs[r][cc] = (gk < k1 && gn < N) ? B[gn * ldb + gk] : 0.f;
            }
        }
        __syncthreads();
        #pragma unroll
        for (int kk = 0; kk < 16; ++kk) {
            float a[4], b[4];
            #pragma unroll
            for (int i = 0; i < 4; ++i) a[i] = As[kk][ty * 4 + i];
            #pragma unroll
            for (int j = 0; j < 4; ++j) b[j] = Bs[kk][tx * 4 + j];
            #pragma unroll
            for (int i = 0; i < 4; ++i)
                #pragma unroll
                for (int j = 0; j < 4; ++j)
                    acc[i][j] = fmaf(a[i], b[j], acc[i][j]);
        }
        __syncthreads();
    }

    const bool split = (gridDim.z > 1);
    #pragma unroll
    for (int i = 0; i < 4; ++i) {
        int gm = m0 + ty * 4 + i;
        if (gm >= M) continue;
        #pragma unroll
        for (int j = 0; j < 4; ++j) {
            int gn = n0 + tx * 4 + j;
            if (gn >= N) continue;
            float v = acc[i][j];
            if (bias != nullptr && z == 0) v += bias[gn];
            if (split) atomicAdd(&C[gm * ldc + gn], v);
            else       C[gm * ldc + gn] = v;
        }
    }
}

// ---------------------------------------------------------------------------
// small utility kernels
// ---------------------------------------------------------------------------
__global__ void zero_f32(float* p, long n) {
    for (long i = (long)blockIdx.x * blockDim.x + threadIdx.x; i < n;
         i += (long)gridDim.x * blockDim.x) p[i] = 0.f;
}
__global__ void zero_i32(int* p, long n) {
    for (long i = (long)blockIdx.x * blockDim.x + threadIdx.x; i < n;
         i += (long)gridDim.x * blockDim.x) p[i] = 0;
}
__global__ void addvec_kernel(const float* a, const float* b, float* o, int n) {
    int i = blockIdx.x * blockDim.x + threadIdx.x;
    if (i < n) o[i] = a[i] + b[i];
}

// CSR build
__global__ void hist_kernel(const int* __restrict__ key, int* counts, int E) {
    int i = blockIdx.x * blockDim.x + threadIdx.x;
    if (i < E) atomicAdd(&counts[key[i]], 1);
}
__global__ __launch_bounds__(256)
void scan_kernel(const int* __restrict__ counts, int* rowptr, int* cursor, int n) {
    __shared__ int buf[256];
    __shared__ int carry_s;
    const int tid = threadIdx.x;
    if (tid == 0) carry_s = 0;
    __syncthreads();
    const int nch = (n + 255) / 256;
    for (int ch = 0; ch < nch; ++ch) {
        int i = ch * 256 + tid;
        int v = (i < n) ? counts[i] : 0;
        buf[tid] = v;
        __syncthreads();
        for (int off = 1; off < 256; off <<= 1) {
            int add = (tid >= off) ? buf[tid - off] : 0;
            __syncthreads();
            buf[tid] += add;
            __syncthreads();
        }
        int incl = buf[tid];
        int base = carry_s;
        if (i < n) {
            rowptr[i + 1] = base + incl;
            cursor[i]     = base + incl - v;
        }
        if (ch == 0 && tid == 0) rowptr[0] = 0;
        __syncthreads();
        if (tid == 255) carry_s = base + incl;
        __syncthreads();
    }
}
__global__ void scatter_kernel(const int* __restrict__ key, const int* __restrict__ val,
                               int* cursor, int* sorted, int E) {
    int i = blockIdx.x * blockDim.x + threadIdx.x;
    if (i < E) {
        int pos = atomicAdd(&cursor[key[i]], 1);
        sorted[pos] = val[i];
    }
}
// per-node aggregation + conv epilogue: xc[n, off+c] = relu(xr[n,c] + sum xn[src,c])
__global__ __launch_bounds__(256)
void agg_conv_kernel(const float* __restrict__ xr, const float* __restrict__ xn,
                     const int* __restrict__ rowptr, const int* __restrict__ sorted,
                     float* __restrict__ xc, int halfOff) {
    const int n = blockIdx.x, tid = threadIdx.x;
    float acc = xr[n * H_GNN + tid];
    const int s = rowptr[n], e = rowptr[n + 1];
    for (int t = s; t < e; ++t) {
        int src = sorted[t];
        acc += xn[src * H_GNN + tid];
    }
    xc[n * D_MLP + halfOff + tid] = fmaxf(acc, 0.f);
}

// column stats over 25600 rows (512 cols)
__global__ __launch_bounds__(512)
void colstat_kernel(const float* __restrict__ h1, float* colsum, float* colsq) {
    const int c = threadIdx.x;
    const int r0 = blockIdx.x * 128;
    float s = 0.f, s2 = 0.f;
    for (int r = 0; r < 128; ++r) {
        float v = h1[(r0 + r) * D_MLP + c];
        s += v; s2 += v * v;
    }
    atomicAdd(&colsum[c], s);
    atomicAdd(&colsq[c], s2);
}
__global__ void finalize_stats(const float* colsum, const float* colsq,
                               const float* gamma, const float* beta,
                               float* scalev, float* shiftv) {
    int c = threadIdx.x;
    float m  = colsum[c] * (1.f / N_NODES);
    float vr = colsq[c] * (1.f / N_NODES) - m * m;
    float g  = gamma[c] * rsqrtf(vr + 1e-5f);
    scalev[c] = g;
    shiftv[c] = beta[c] - m * g;
}
__global__ void norm_relu(float* h, const float* __restrict__ sc,
                          const float* __restrict__ sh, long n) {
    for (long i = (long)blockIdx.x * blockDim.x + threadIdx.x; i < n;
         i += (long)gridDim.x * blockDim.x) {
        int c = (int)(i & 511);
        h[i] = fmaxf(fmaf(h[i], sc[c], sh[c]), 0.f);
    }
}
__global__ __launch_bounds__(512)
void pool_kernel(const float* __restrict__ hrelu, float* P) {
    const int b = blockIdx.x, c = threadIdx.x;
    float s = 0.f;
    for (int i = 0; i < NPG_; ++i) s += hrelu[(b * NPG_ + i) * D_MLP + c];
    P[b * D_MLP + c] = s * (1.f / NPG_);
}
// sW[l,p] = dot(c0[l,:], W_alm[p, 0:512])
__global__ void sw_kernel(const float* __restrict__ c0, const float* __restrict__ W_alm,
                          float* sW) {
    int i = blockIdx.x * blockDim.x + threadIdx.x;
    if (i < 2 * NPG_) {
        int l = i / NPG_, p = i % NPG_;
        float s = 0.f;
        for (int k = 0; k < R_LSTM; ++k) s += c0[l * R_LSTM + k] * W_alm[p * 51712 + k];
        sW[l * NPG_ + p] = s;
    }
}
__global__ __launch_bounds__(128)
void alpha_kernel(const float* __restrict__ sW, const float* __restrict__ hW,
                  const float* __restrict__ b_alm, float* __restrict__ alpha) {
    const int lb = blockIdx.x;          // l*256 + b
    const int l = lb >> 8, b = lb & 255;
    const int p = threadIdx.x;
    __shared__ float red[128];
    float v = 0.f;
    if (p < NPG_) v = sW[l * NPG_ + p] + hW[b * NPG_ + p] + b_alm[p];
    red[p] = v;
    __syncthreads();
    for (int s = 64; s > 0; s >>= 1) {
        if (p < s) red[p] += red[p + s];
        __syncthreads();
    }
    float inv = 1.f / red[0];
    if (p < NPG_) alpha[lb * NPG_ + p] = v * inv;
}
__global__ __launch_bounds__(512)
void newc_kernel(const float* __restrict__ alpha, const float* __restrict__ xc,
                 float* new_c) {
    const int l = blockIdx.y, chunk = blockIdx.x, c = threadIdx.x;
    const int r0 = chunk * 800;
    float acc = 0.f;
    for (int r = r0; r < r0 + 800; ++r)
        acc += alpha[l * N_NODES + r] * xc[r * D_MLP + c];
    atomicAdd(&new_c[l * D_MLP + c], acc);
}

// ---------------------------------------------------------------------------
// Persistent 2-layer LSTM, 256 sequential steps, batch 1.
// Data-as-canary sync: h-state buffers pre-filled with CANARY bits each call;
// producers write h via RELAXED agent-scope stores (plain LLC write-through,
// NO acquire/release cache maintenance, NO flag RMW); consumers poll-load
// their input slice and retry while any word == CANARY. No ordering
// assumptions: each word independently transitions canary -> real.
//
// 64 blocks x 512 threads. Blocks 0..31 = layer0 (16 h each), 32..63 = layer1.
// Row-per-lane, k-chunk-per-wave GEMV: weights live in VGPRs (loaded once),
// h broadcast via __shfl with literal lane -> v_readlane + FMA (no LDS in
// the inner loop). Cross-wave reduce via double-buffered LDS partials.
// ---------------------------------------------------------------------------
#define CANARY 0x7FC00000u
#define SPIN_MAX 20000

__device__ __forceinline__ unsigned coh_load_u(const unsigned* p) {
    return __hip_atomic_load(p, __ATOMIC_RELAXED, __HIP_MEMORY_SCOPE_AGENT);
}
__device__ __forceinline__ void coh_store_f(float* p, float v) {
    __hip_atomic_store(p, v, __ATOMIC_RELAXED, __HIP_MEMORY_SCOPE_AGENT);
}

__global__ void lstm_init_kernel(const float* __restrict__ h0,
                                 float* h0buf, float* h1buf) {
    int i = blockIdx.x * blockDim.x + threadIdx.x;
    if (i < 512) { h0buf[i] = h0[i]; h1buf[i] = h0[512 + i]; }
    for (int j = 512 + i; j < 257 * 512; j += gridDim.x * blockDim.x) {
        ((unsigned*)h0buf)[j] = CANARY;
        ((unsigned*)h1buf)[j] = CANARY;
    }
}

__global__ __launch_bounds__(512)
void lstm_kernel(const float* __restrict__ inp0, const float* __restrict__ Whh0,
                 const float* __restrict__ Wih1, const float* __restrict__ Whh1,
                 const float* __restrict__ b1s, const float* __restrict__ new_c,
                 float* h0buf, float* h1buf)
{
    const int tid  = threadIdx.x;
    const int lane = tid & 63;
    const int w    = tid >> 6;            // wave 0..7 = k-chunk
    const int blk  = blockIdx.x;
    const int layer = blk >> 5;
    const int base  = (blk & 31) * 16;    // this block's 16 h indices
    const int gate  = lane >> 4;          // 0=i 1=f 2=g 3=o
    const int hid   = lane & 15;
    const int rowg  = gate * 512 + base + hid;   // weight row for this lane

    __shared__ float partial[2][8][64];

    if (layer == 0) {
        // --- layer 0: k = 512, chunk 64/wave, weights Whh0[rowg][w*64..+64)
        float wr[64];
        {
            const float4* wp = (const float4*)(Whh0 + (long)rowg * 512 + w * 64);
            #pragma unroll
            for (int i = 0; i < 16; ++i) {
                float4 v = wp[i];
                wr[4*i] = v.x; wr[4*i+1] = v.y; wr[4*i+2] = v.z; wr[4*i+3] = v.w;
            }
        }
        float c = (w == 0 && lane < 16) ? new_c[base + lane] : 0.f;
        const unsigned* src_u = (const unsigned*)h0buf + w * 64 + lane;
        for (int t = 0; t < 256; ++t) {
            unsigned hu; int guard = 0;
            for (;;) {
                hu = coh_load_u(src_u + t * 512);
                if (!__any(hu == CANARY)) break;
                if (++guard > SPIN_MAX) break;
                __builtin_amdgcn_s_sleep(1);
            }
            float hv = __uint_as_float(hu);
            float ipv = (w == 0) ? inp0[t * 2048 + rowg] : 0.f;  // prefetch
            float acc = 0.f;
            #pragma unroll
            for (int j = 0; j < 64; ++j)
                acc = fmaf(wr[j], __shfl(hv, j), acc);
            partial[t & 1][w][lane] = acc;
            __syncthreads();
            if (w == 0) {
                float g = ipv;
                #pragma unroll
                for (int ww = 0; ww < 8; ++ww) g += partial[t & 1][ww][lane];
                float a = (gate == 2) ? tanhf(g) : 1.f / (1.f + expf(-g));
                float fv = __shfl(a, lane + 16);
                float gv = __shfl(a, lane + 32);
                float ov = __shfl(a, lane + 48);
                if (lane < 16) {
                    c = fv * c + a * gv;     // a == i-gate for lanes 0..15
                    float h = ov * tanhf(c);
                    coh_store_f(h0buf + (t + 1) * 512 + base + lane, h);
                }
            }
        }
    } else {
        // --- layer 1: k = 1024 (x=h0[t+1] || h=h1[t]), chunk 128/wave
        const float* Wsel = (w < 4) ? Wih1 : Whh1;
        const int koff = (w & 3) * 128;
        float wrA[64], wrB[64];
        {
            const float4* wp = (const float4*)(Wsel + (long)rowg * 512 + koff);
            #pragma unroll
            for (int i = 0; i < 16; ++i) {
                float4 v = wp[i];
                wrA[4*i] = v.x; wrA[4*i+1] = v.y; wrA[4*i+2] = v.z; wrA[4*i+3] = v.w;
            }
            #pragma unroll
            for (int i = 0; i < 16; ++i) {
                float4 v = wp[16 + i];
                wrB[4*i] = v.x; wrB[4*i+1] = v.y; wrB[4*i+2] = v.z; wrB[4*i+3] = v.w;
            }
        }
        float bsum = (w == 0) ? b1s[rowg] : 0.f;
        float c = (w == 0 && lane < 16) ? new_c[512 + base + lane] : 0.f;
        for (int t = 0; t < 256; ++t) {
            const unsigned* xsrc = (w < 4)
                ? (const unsigned*)h0buf + (t + 1) * 512 + koff
                : (const unsigned*)h1buf + t * 512 + koff;
            unsigned hu0, hu1; int guard = 0;
            for (;;) {
                hu0 = coh_load_u(xsrc + lane);
                hu1 = coh_load_u(xsrc + 64 + lane);
                if (!__any((hu0 == CANARY) || (hu1 == CANARY))) break;
                if (++guard > SPIN_MAX) break;
                __builtin_amdgcn_s_sleep(1);
            }
            float hv0 = __uint_as_float(hu0), hv1 = __uint_as_float(hu1);
            float acc = 0.f;
            #pragma unroll
            for (int j = 0; j < 64; ++j)
                acc = fmaf(wrA[j], __shfl(hv0, j), acc);
            #pragma unroll
            for (int j = 0; j < 64; ++j)
                acc = fmaf(wrB[j], __shfl(hv1, j), acc);
            partial[t & 1][w][lane] = acc;
            __syncthreads();
            if (w == 0) {
                float g = bsum;
                #pragma unroll
                for (int ww = 0; ww < 8; ++ww) g += partial[t & 1][ww][lane];
                float a = (gate == 2) ? tanhf(g) : 1.f / (1.f + expf(-g));
                float fv = __shfl(a, lane + 16);
                float gv = __shfl(a, lane + 32);
                float ov = __shfl(a, lane + 48);
                if (lane < 16) {
                    c = fv * c + a * gv;
                    float h = ov * tanhf(c);
                    coh_store_f(h1buf + (t + 1) * 512 + base + lane, h);
                }
            }
        }
    }
}

// ---------------------------------------------------------------------------
extern "C" void kernel_launch(void* const* d_in, const int* in_sizes, int n_in,
                              void* d_out, int out_size, void* d_ws, size_t ws_size,
                              hipStream_t stream)
{
    const float* x      = (const float*)d_in[0];
    const int*   ei     = (const int*)d_in[1];
    const float* h0     = (const float*)d_in[4];
    const float* c0     = (const float*)d_in[5];
    const float* W_gnn  = (const float*)d_in[6];
    const float* W_root = (const float*)d_in[7];
    const float* W_nbr  = (const float*)d_in[8];
    const float* b_conv = (const float*)d_in[9];
    const float* W1     = (const float*)d_in[10];
    const float* b1     = (const float*)d_in[11];
    const float* gamma  = (const float*)d_in[12];
    const float* beta   = (const float*)d_in[13];
    const float* W2     = (const float*)d_in[14];
    const float* b2     = (const float*)d_in[15];
    const float* W_alm  = (const float*)d_in[16];
    const float* b_alm  = (const float*)d_in[17];
    const float* Wih0   = (const float*)d_in[18];
    const float* Whh0   = (const float*)d_in[19];
    const float* bih0   = (const float*)d_in[20];
    const float* bhh0   = (const float*)d_in[21];
    const float* Wih1   = (const float*)d_in[22];
    const float* Whh1   = (const float*)d_in[23];
    const float* bih1   = (const float*)d_in[24];
    const float* bhh1   = (const float*)d_in[25];
    const float* W_fc   = (const float*)d_in[26];
    const float* b_fc   = (const float*)d_in[27];
    float* out = (float*)d_out;
    float* ws  = (float*)d_ws;

    const int* ei0 = ei;            // src
    const int* ei1 = ei + E_EDGE;   // dst

    // ---- workspace layout (floats) ----
    float* xr = ws;                       // 25600x256
    float* xn = ws + 6553600L;            // 25600x256
    float* xc = ws + 13107200L;           // 25600x512 (lives long)
    float* h1m = ws;                      // 25600x512, overlays xr+xn (both dead)
    long o = 26214400L;
    float* Wgr   = ws + o; o += 32768;    // 128x256
    float* Wgn   = ws + o; o += 32768;
    int*   counts= (int*)(ws + o); o += 25600;
    int*   rowptr= (int*)(ws + o); o += 25601;
    int*   cursor= (int*)(ws + o); o += 25600;
    int*   sorted= (int*)(ws + o); o += 409600;
    float* colsum= ws + o; o += 512;
    float* colsq = ws + o; o += 512;
    float* scalev= ws + o; o += 512;
    float* shiftv= ws + o; o += 512;
    float* P     = ws + o; o += 131072;   // 256x512
    float* x_g   = ws + o; o += 131072;   // 256x512
    float* hW    = ws + o; o += 25600;    // 256x100
    float* sW    = ws + o; o += 200;
    float* alphav= ws + o; o += 51200;    // 2x256x100
    float* newc  = ws + o; o += 1024;     // 2x512
    float* b0s   = ws + o; o += 2048;
    float* b1s   = ws + o; o += 2048;
    float* inp0  = ws + o; o += 524288;   // 256x2048
    float* h0st  = ws + o; o += 131584;   // 257x512
    float* h1st  = ws + o; o += 131584;

    // 1. fold W_gnn into conv weights: Wgr = W_gnn@W_root, Wgn = W_gnn@W_nbr
    gemm_tile<false><<<dim3(4, 2, 1), 256, 0, stream>>>(W_gnn, W_root, Wgr, nullptr,
        128, 256, 256, 256, 256, 256, 256);
    gemm_tile<false><<<dim3(4, 2, 1), 256, 0, stream>>>(W_gnn, W_nbr, Wgn, nullptr,
        128, 256, 256, 256, 256, 256, 256);
    // 2. xr = x@Wgr + b_conv ; xn = x@Wgn
    gemm_tile<false><<<dim3(4, 400, 1), 256, 0, stream>>>(x, Wgr, xr, b_conv,
        N_NODES, 256, 128, 128, 256, 256, 128);
    gemm_tile<false><<<dim3(4, 400, 1), 256, 0, stream>>>(x, Wgn, xn, nullptr,
        N_NODES, 256, 128, 128, 256, 256, 128);
    // 3. forward conv: CSR by dst, gather xn[src]
    zero_i32<<<dim3(100), 256, 0, stream>>>(counts, 25600);
    hist_kernel<<<dim3(1600), 256, 0, stream>>>(ei1, counts, E_EDGE);
    scan_kernel<<<dim3(1), 256, 0, stream>>>(counts, rowptr, cursor, 25600);
    scatter_kernel<<<dim3(1600), 256, 0, stream>>>(ei1, ei0, cursor, sorted, E_EDGE);
    agg_conv_kernel<<<dim3(25600), 256, 0, stream>>>(xr, xn, rowptr, sorted, xc, 0);
    // 4. backward conv: CSR by src, gather xn[dst]
    zero_i32<<<dim3(100), 256, 0, stream>>>(counts, 25600);
    hist_kernel<<<dim3(1600), 256, 0, stream>>>(ei0, counts, E_EDGE);
    scan_kernel<<<dim3(1), 256, 0, stream>>>(counts, rowptr, cursor, 25600);
    scatter_kernel<<<dim3(1600), 256, 0, stream>>>(ei0, ei1, cursor, sorted, E_EDGE);
    agg_conv_kernel<<<dim3(25600), 256, 0, stream>>>(xr, xn, rowptr, sorted, xc, 256);
    // 5. h1 = xc@W1 + b1  (into overlay region)
    gemm_tile<false><<<dim3(8, 400, 1), 256, 0, stream>>>(xc, W1, h1m, b1,
        N_NODES, 512, 512, 512, 512, 512, 512);
    // 6. per-column layernorm + relu (in place)
    zero_f32<<<dim3(4), 256, 0, stream>>>(colsum, 1024);
    colstat_kernel<<<dim3(200), 512, 0, stream>>>(h1m, colsum, colsq);
    finalize_stats<<<dim3(1), 512, 0, stream>>>(colsum, colsq, gamma, beta, scalev, shiftv);
    norm_relu<<<dim3(2048), 256, 0, stream>>>(h1m, scalev, shiftv, (long)N_NODES * 512);
    // 7. graph mean-pool, then x_g = P@W2 + b2 (pool-before-GEMM)
    pool_kernel<<<dim3(256), 512, 0, stream>>>(h1m, P);
    gemm_tile<false><<<dim3(8, 4, 1), 256, 0, stream>>>(P, W2, x_g, b2,
        256, 512, 512, 512, 512, 512, 512);
    // 8. hW = xc_flat(256x51200) @ Wh^T  (split-K)
    zero_f32<<<dim3(25), 256, 0, stream>>>(hW, 25600);
    gemm_tile<true><<<dim3(2, 4, 32), 256, 0, stream>>>(xc, W_alm + 512, hW, nullptr,
        256, 100, 51200, 51200, 51712, 100, 1600);
    // 9. alpha and new_c
    sw_kernel<<<dim3(1), 256, 0, stream>>>(c0, W_alm, sW);
    alpha_kernel<<<dim3(512), 128, 0, stream>>>(sW, hW, b_alm, alphav);
    zero_f32<<<dim3(1), 256, 0, stream>>>(newc, 1024);
    newc_kernel<<<dim3(32, 2), 512, 0, stream>>>(alphav, xc, newc);
    // 10. LSTM input projection (layer 0, all steps) + bias sums
    addvec_kernel<<<dim3(8), 256, 0, stream>>>(bih0, bhh0, b0s, 2048);
    addvec_kernel<<<dim3(8), 256, 0, stream>>>(bih1, bhh1, b1s, 2048);
    gemm_tile<true><<<dim3(32, 4, 1), 256, 0, stream>>>(x_g, Wih0, inp0, b0s,
        256, 2048, 512, 512, 512, 2048, 512);
    // 11. persistent 2-layer LSTM (canary-sync)
    lstm_init_kernel<<<dim3(64), 512, 0, stream>>>(h0, h0st, h1st);
    lstm_kernel<<<dim3(64), 512, 0, stream>>>(inp0, Whh0, Wih1, Whh1, b1s, newc,
                                              h0st, h1st);
    // 12. preds = outs1 @ W_fc + b_fc
    gemm_tile<false><<<dim3(500, 4, 1), 256, 0, stream>>>(h1st + 512, W_fc, out, b_fc,
        256, V_OUT, 512, 512, V_OUT, V_OUT, 512);
}

// Round 5
// 2205.783 us; speedup vs baseline: 1.9327x; 1.1138x over previous
//
#include <hip/hip_runtime.h>
#include <math.h>

#define N_NODES 25600
#define F_IN    128
#define H_GNN   256
#define D_MLP   512
#define E_EDGE  409600
#define B_GR    256
#define NPG_    100
#define R_LSTM  512
#define V_OUT   32000

typedef __bf16 bf16x8 __attribute__((ext_vector_type(8)));
typedef float  f32x4  __attribute__((ext_vector_type(4)));
typedef unsigned short u16x8 __attribute__((ext_vector_type(8)));

__device__ __forceinline__ unsigned short f2bf(float x) {
    unsigned u = __builtin_bit_cast(unsigned, x);
    unsigned r = (u + 0x7FFFu + ((u >> 16) & 1u)) >> 16;
    return (unsigned short)r;
}

// ---------------------------------------------------------------------------
// Generic f32 tiled GEMM — used for every GEMM on the LSTM-input (chaos) path.
// ---------------------------------------------------------------------------
template<bool TRANSB>
__global__ __launch_bounds__(256)
void gemm_tile(const float* __restrict__ A, const float* __restrict__ B,
               float* __restrict__ C, const float* __restrict__ bias,
               int M, int N, int K, int lda, int ldb, int ldc, int kChunk)
{
    __shared__ float As[16][68];
    __shared__ float Bs[16][68];
    const int tid = threadIdx.x;
    const int n0 = blockIdx.x * 64;
    const int m0 = blockIdx.y * 64;
    const int z  = blockIdx.z;
    const int k0 = z * kChunk;
    const int k1 = min(K, k0 + kChunk);
    const int ty = tid >> 4, tx = tid & 15;
    float acc[4][4] = {};

    for (int kb = k0; kb < k1; kb += 16) {
        {
            const int r = tid >> 4, c = tid & 15;
            #pragma unroll
            for (int i = 0; i < 4; ++i) {
                int rr = r + i * 16;
                int gm = m0 + rr, gk = kb + c;
                As[c][rr] = (gm < M && gk < k1) ? A[gm * lda + gk] : 0.f;
            }
        }
        if (!TRANSB) {
            const int r = tid >> 6, c = tid & 63;
            #pragma unroll
            for (int i = 0; i < 4; ++i) {
                int rr = r + i * 4;
                int gk = kb + rr, gn = n0 + c;
                Bs[rr][c] = (gk < k1 && gn < N) ? B[gk * ldb + gn] : 0.f;
            }
        } else {
            const int r = tid & 15, c = tid >> 4;
            #pragma unroll
            for (int i = 0; i < 4; ++i) {
                int cc = c + i * 16;
                int gk = kb + r, gn = n0 + cc;
                Bs[r][cc] = (gk < k1 && gn < N) ? B[gn * ldb + gk] : 0.f;
            }
        }
        __syncthreads();
        #pragma unroll
        for (int kk = 0; kk < 16; ++kk) {
            float a[4], b[4];
            #pragma unroll
            for (int i = 0; i < 4; ++i) a[i] = As[kk][ty * 4 + i];
            #pragma unroll
            for (int j = 0; j < 4; ++j) b[j] = Bs[kk][tx * 4 + j];
            #pragma unroll
            for (int i = 0; i < 4; ++i)
                #pragma unroll
                for (int j = 0; j < 4; ++j)
                    acc[i][j] = fmaf(a[i], b[j], acc[i][j]);
        }
        __syncthreads();
    }

    const bool split = (gridDim.z > 1);
    #pragma unroll
    for (int i = 0; i < 4; ++i) {
        int gm = m0 + ty * 4 + i;
        if (gm >= M) continue;
        #pragma unroll
        for (int j = 0; j < 4; ++j) {
            int gn = n0 + tx * 4 + j;
            if (gn >= N) continue;
            float v = acc[i][j];
            if (bias != nullptr && z == 0) v += bias[gn];
            if (split) atomicAdd(&C[gm * ldc + gn], v);
            else       C[gm * ldc + gn] = v;
        }
    }
}

// ---------------------------------------------------------------------------
// bf16 MFMA GEMM: C[M,N](f32) = A[M,K](bf16,row-major) @ Bt[N,K](bf16)^T.
// Used ONLY for chaos-safe GEMMs (hW attention, preds leaf).
// ---------------------------------------------------------------------------
__global__ __launch_bounds__(256)
void mfma_gemm(const unsigned short* __restrict__ A,
               const unsigned short* __restrict__ Bt,
               float* __restrict__ C, const float* __restrict__ bias,
               int M, int N, int K, int lda, int ldb, int ldc, int kChunk)
{
    __shared__ unsigned short As[128][40];
    __shared__ unsigned short Bs[128][40];
    const int tid  = threadIdx.x;
    const int lane = tid & 63;
    const int wv   = tid >> 6;
    const int wr   = wv >> 1, wc = wv & 1;
    const int n0 = blockIdx.x * 128;
    const int m0 = blockIdx.y * 128;
    const int z  = blockIdx.z;
    const int k0 = z * kChunk;
    const int k1 = min(K, k0 + kChunk);

    const int srow = tid >> 2;
    const int skoff = (tid & 3) * 8;

    f32x4 acc[4][4] = {};

    for (int kb = k0; kb < k1; kb += 32) {
        #pragma unroll
        for (int p = 0; p < 2; ++p) {
            int row = p * 64 + srow;
            u16x8 va = *(const u16x8*)(A + (long)(m0 + row) * lda + kb + skoff);
            *(u16x8*)&As[row][skoff] = va;
            int gb = n0 + row;
            u16x8 vb = {0, 0, 0, 0, 0, 0, 0, 0};
            if (gb < N) vb = *(const u16x8*)(Bt + (long)gb * ldb + kb + skoff);
            *(u16x8*)&Bs[row][skoff] = vb;
        }
        __syncthreads();
        bf16x8 af[4], bfr[4];
        #pragma unroll
        for (int fm = 0; fm < 4; ++fm)
            af[fm] = *(const bf16x8*)&As[wr * 64 + fm * 16 + (lane & 15)][(lane >> 4) * 8];
        #pragma unroll
        for (int fn = 0; fn < 4; ++fn)
            bfr[fn] = *(const bf16x8*)&Bs[wc * 64 + fn * 16 + (lane & 15)][(lane >> 4) * 8];
        #pragma unroll
        for (int fm = 0; fm < 4; ++fm)
            #pragma unroll
            for (int fn = 0; fn < 4; ++fn)
                acc[fm][fn] = __builtin_amdgcn_mfma_f32_16x16x32_bf16(
                    af[fm], bfr[fn], acc[fm][fn], 0, 0, 0);
        __syncthreads();
    }

    const bool split = (gridDim.z > 1);
    #pragma unroll
    for (int fm = 0; fm < 4; ++fm) {
        int row = m0 + wr * 64 + fm * 16 + ((lane >> 4) << 2);
        #pragma unroll
        for (int fn = 0; fn < 4; ++fn) {
            int col = n0 + wc * 64 + fn * 16 + (lane & 15);
            if (col >= N) continue;
            f32x4 v = acc[fm][fn];
            #pragma unroll
            for (int r = 0; r < 4; ++r) {
                float o = v[r];
                if (bias != nullptr && z == 0) o += bias[col];
                if (split) atomicAdd(&C[(long)(row + r) * ldc + col], o);
                else       C[(long)(row + r) * ldc + col] = o;
            }
        }
    }
}

// ---------------------------------------------------------------------------
// cast / transpose kernels
// ---------------------------------------------------------------------------
__global__ void castbf(const float* __restrict__ in, unsigned short* __restrict__ out,
                       long n) {
    long stride = (long)gridDim.x * blockDim.x * 4;
    for (long j = ((long)blockIdx.x * blockDim.x + threadIdx.x) * 4; j < n; j += stride) {
        float4 v = *(const float4*)(in + j);
        ushort4 o;
        o.x = f2bf(v.x); o.y = f2bf(v.y); o.z = f2bf(v.z); o.w = f2bf(v.w);
        *(ushort4*)(out + j) = o;
    }
}
__global__ void cast_strided(const float* __restrict__ in, unsigned short* __restrict__ out,
                             int cols, long ldin, long off) {
    const int r = blockIdx.y;
    int c = (blockIdx.x * blockDim.x + threadIdx.x) * 4;
    if (c < cols) {
        float4 v = *(const float4*)(in + (long)r * ldin + off + c);
        ushort4 o;
        o.x = f2bf(v.x); o.y = f2bf(v.y); o.z = f2bf(v.z); o.w = f2bf(v.w);
        *(ushort4*)(out + (long)r * cols + c) = o;
    }
}
__global__ __launch_bounds__(256)
void transcast(const float* __restrict__ in, unsigned short* __restrict__ out,
               int R, int C) {
    __shared__ unsigned short t[64][72];
    const int c0 = blockIdx.x * 64, r0 = blockIdx.y * 64;
    const int tid = threadIdx.x;
    const int rr = tid >> 2, cg = (tid & 3) * 16;
    #pragma unroll
    for (int i = 0; i < 4; ++i) {
        float4 v = *(const float4*)(in + (long)(r0 + rr) * C + c0 + cg + i * 4);
        t[cg + i * 4 + 0][rr] = f2bf(v.x);
        t[cg + i * 4 + 1][rr] = f2bf(v.y);
        t[cg + i * 4 + 2][rr] = f2bf(v.z);
        t[cg + i * 4 + 3][rr] = f2bf(v.w);
    }
    __syncthreads();
    const int cc = tid >> 2, kg = (tid & 3) * 16;
    #pragma unroll
    for (int i = 0; i < 2; ++i) {
        u16x8 v = *(const u16x8*)&t[cc][kg + i * 8];
        *(u16x8*)(out + (long)(c0 + cc) * R + r0 + kg + i * 8) = v;
    }
}

// ---------------------------------------------------------------------------
// small utility kernels
// ---------------------------------------------------------------------------
__global__ void zero_f32(float* p, long n) {
    for (long i = (long)blockIdx.x * blockDim.x + threadIdx.x; i < n;
         i += (long)gridDim.x * blockDim.x) p[i] = 0.f;
}
__global__ void zero_i32(int* p, long n) {
    for (long i = (long)blockIdx.x * blockDim.x + threadIdx.x; i < n;
         i += (long)gridDim.x * blockDim.x) p[i] = 0;
}
__global__ void addvec_kernel(const float* a, const float* b, float* o, int n) {
    int i = blockIdx.x * blockDim.x + threadIdx.x;
    if (i < n) o[i] = a[i] + b[i];
}

// CSR build
__global__ void hist_kernel(const int* __restrict__ key, int* counts, int E) {
    int i = blockIdx.x * blockDim.x + threadIdx.x;
    if (i < E) atomicAdd(&counts[key[i]], 1);
}
__global__ __launch_bounds__(256)
void scan_kernel(const int* __restrict__ counts, int* rowptr, int* cursor, int n) {
    __shared__ int buf[256];
    __shared__ int carry_s;
    const int tid = threadIdx.x;
    if (tid == 0) carry_s = 0;
    __syncthreads();
    const int nch = (n + 255) / 256;
    for (int ch = 0; ch < nch; ++ch) {
        int i = ch * 256 + tid;
        int v = (i < n) ? counts[i] : 0;
        buf[tid] = v;
        __syncthreads();
        for (int off = 1; off < 256; off <<= 1) {
            int add = (tid >= off) ? buf[tid - off] : 0;
            __syncthreads();
            buf[tid] += add;
            __syncthreads();
        }
        int incl = buf[tid];
        int base = carry_s;
        if (i < n) {
            rowptr[i + 1] = base + incl;
            cursor[i]     = base + incl - v;
        }
        if (ch == 0 && tid == 0) rowptr[0] = 0;
        __syncthreads();
        if (tid == 255) carry_s = base + incl;
        __syncthreads();
    }
}
__global__ void scatter_kernel(const int* __restrict__ key, const int* __restrict__ val,
                               int* cursor, int* sorted, int E) {
    int i = blockIdx.x * blockDim.x + threadIdx.x;
    if (i < E) {
        int pos = atomicAdd(&cursor[key[i]], 1);
        sorted[pos] = val[i];
    }
}
__global__ __launch_bounds__(256)
void agg_conv_kernel(const float* __restrict__ xr, const float* __restrict__ xn,
                     const int* __restrict__ rowptr, const int* __restrict__ sorted,
                     float* __restrict__ xc, int halfOff) {
    const int n = blockIdx.x, tid = threadIdx.x;
    float acc = xr[n * H_GNN + tid];
    const int s = rowptr[n], e = rowptr[n + 1];
    for (int t = s; t < e; ++t) {
        int src = sorted[t];
        acc += xn[src * H_GNN + tid];
    }
    xc[n * D_MLP + halfOff + tid] = fmaxf(acc, 0.f);
}

__global__ __launch_bounds__(512)
void colstat_kernel(const float* __restrict__ h1, float* colsum, float* colsq) {
    const int c = threadIdx.x;
    const int r0 = blockIdx.x * 128;
    float s = 0.f, s2 = 0.f;
    for (int r = 0; r < 128; ++r) {
        float v = h1[(r0 + r) * D_MLP + c];
        s += v; s2 += v * v;
    }
    atomicAdd(&colsum[c], s);
    atomicAdd(&colsq[c], s2);
}
__global__ void finalize_stats(const float* colsum, const float* colsq,
                               const float* gamma, const float* beta,
                               float* scalev, float* shiftv) {
    int c = threadIdx.x;
    float m  = colsum[c] * (1.f / N_NODES);
    float vr = colsq[c] * (1.f / N_NODES) - m * m;
    float g  = gamma[c] * rsqrtf(vr + 1e-5f);
    scalev[c] = g;
    shiftv[c] = beta[c] - m * g;
}
__global__ void norm_relu(float* h, const float* __restrict__ sc,
                          const float* __restrict__ sh, long n) {
    for (long i = (long)blockIdx.x * blockDim.x + threadIdx.x; i < n;
         i += (long)gridDim.x * blockDim.x) {
        int c = (int)(i & 511);
        h[i] = fmaxf(fmaf(h[i], sc[c], sh[c]), 0.f);
    }
}
__global__ __launch_bounds__(512)
void pool_kernel(const float* __restrict__ hrelu, float* P) {
    const int b = blockIdx.x, c = threadIdx.x;
    float s = 0.f;
    for (int i = 0; i < NPG_; ++i) s += hrelu[(b * NPG_ + i) * D_MLP + c];
    P[b * D_MLP + c] = s * (1.f / NPG_);
}
__global__ void sw_kernel(const float* __restrict__ c0, const float* __restrict__ W_alm,
                          float* sW) {
    int i = blockIdx.x * blockDim.x + threadIdx.x;
    if (i < 2 * NPG_) {
        int l = i / NPG_, p = i % NPG_;
        float s = 0.f;
        for (int k = 0; k < R_LSTM; ++k) s += c0[l * R_LSTM + k] * W_alm[p * 51712 + k];
        sW[l * NPG_ + p] = s;
    }
}
__global__ __launch_bounds__(128)
void alpha_kernel(const float* __restrict__ sW, const float* __restrict__ hW,
                  const float* __restrict__ b_alm, float* __restrict__ alpha) {
    const int lb = blockIdx.x;
    const int l = lb >> 8, b = lb & 255;
    const int p = threadIdx.x;
    __shared__ float red[128];
    float v = 0.f;
    if (p < NPG_) v = sW[l * NPG_ + p] + hW[b * NPG_ + p] + b_alm[p];
    red[p] = v;
    __syncthreads();
    for (int s = 64; s > 0; s >>= 1) {
        if (p < s) red[p] += red[p + s];
        __syncthreads();
    }
    float inv = 1.f / red[0];
    if (p < NPG_) alpha[lb * NPG_ + p] = v * inv;
}
__global__ __launch_bounds__(512)
void newc_kernel(const float* __restrict__ alpha, const float* __restrict__ xc,
                 float* new_c) {
    const int l = blockIdx.y, chunk = blockIdx.x, c = threadIdx.x;
    const int r0 = chunk * 800;
    float acc = 0.f;
    for (int r = r0; r < r0 + 800; ++r)
        acc += alpha[l * N_NODES + r] * xc[r * D_MLP + c];
    atomicAdd(&new_c[l * D_MLP + c], acc);
}

// ---------------------------------------------------------------------------
// Persistent 2-layer LSTM, canary sync. PRECISE libm transcendentals
// (tanhf/expf) — the 256-step recurrence is chaotic (amplifies input/step
// perturbations ~500-1000x), so the LSTM and everything feeding it stays
// in exact f32. Tight poll (no s_sleep first 32 iters) + inp0 prefetch.
// ---------------------------------------------------------------------------
#define CANARY 0x7FC00000u
#define SPIN_MAX 20000

__device__ __forceinline__ unsigned coh_load_u(const unsigned* p) {
    return __hip_atomic_load(p, __ATOMIC_RELAXED, __HIP_MEMORY_SCOPE_AGENT);
}
__device__ __forceinline__ void coh_store_f(float* p, float v) {
    __hip_atomic_store(p, v, __ATOMIC_RELAXED, __HIP_MEMORY_SCOPE_AGENT);
}

__global__ void lstm_init_kernel(const float* __restrict__ h0,
                                 float* h0buf, float* h1buf) {
    int i = blockIdx.x * blockDim.x + threadIdx.x;
    if (i < 512) { h0buf[i] = h0[i]; h1buf[i] = h0[512 + i]; }
    for (int j = 512 + i; j < 257 * 512; j += gridDim.x * blockDim.x) {
        ((unsigned*)h0buf)[j] = CANARY;
        ((unsigned*)h1buf)[j] = CANARY;
    }
}

__global__ __launch_bounds__(512)
void lstm_kernel(const float* __restrict__ inp0, const float* __restrict__ Whh0,
                 const float* __restrict__ Wih1, const float* __restrict__ Whh1,
                 const float* __restrict__ b1s, const float* __restrict__ new_c,
                 float* h0buf, float* h1buf)
{
    const int tid  = threadIdx.x;
    const int lane = tid & 63;
    const int w    = tid >> 6;
    const int blk  = blockIdx.x;
    const int layer = blk >> 5;
    const int base  = (blk & 31) * 16;
    const int gate  = lane >> 4;
    const int hid   = lane & 15;
    const int rowg  = gate * 512 + base + hid;

    __shared__ float partial[2][8][64];

    if (layer == 0) {
        float wr[64];
        {
            const float4* wp = (const float4*)(Whh0 + (long)rowg * 512 + w * 64);
            #pragma unroll
            for (int i = 0; i < 16; ++i) {
                float4 v = wp[i];
                wr[4*i] = v.x; wr[4*i+1] = v.y; wr[4*i+2] = v.z; wr[4*i+3] = v.w;
            }
        }
        float c = (w == 0 && lane < 16) ? new_c[base + lane] : 0.f;
        const unsigned* src_u = (const unsigned*)h0buf + w * 64 + lane;
        for (int t = 0; t < 256; ++t) {
            float ipv = (w == 0) ? inp0[t * 2048 + rowg] : 0.f;  // prefetch (pre-poll)
            unsigned hu; int guard = 0;
            for (;;) {
                hu = coh_load_u(src_u + t * 512);
                if (!__any(hu == CANARY)) break;
                if (++guard > SPIN_MAX) break;
                if (guard > 32) __builtin_amdgcn_s_sleep(1);
            }
            float hv = __uint_as_float(hu);
            float acc = 0.f;
            #pragma unroll
            for (int j = 0; j < 64; ++j)
                acc = fmaf(wr[j], __shfl(hv, j), acc);
            partial[t & 1][w][lane] = acc;
            __syncthreads();
            if (w == 0) {
                float g = ipv;
                #pragma unroll
                for (int ww = 0; ww < 8; ++ww) g += partial[t & 1][ww][lane];
                float a = (gate == 2) ? tanhf(g) : 1.f / (1.f + expf(-g));
                float fv = __shfl(a, lane + 16);
                float gv = __shfl(a, lane + 32);
                float ov = __shfl(a, lane + 48);
                if (lane < 16) {
                    c = fv * c + a * gv;
                    float h = ov * tanhf(c);
                    coh_store_f(h0buf + (t + 1) * 512 + base + lane, h);
                }
            }
        }
    } else {
        const float* Wsel = (w < 4) ? Wih1 : Whh1;
        const int koff = (w & 3) * 128;
        float wrA[64], wrB[64];
        {
            const float4* wp = (const float4*)(Wsel + (long)rowg * 512 + koff);
            #pragma unroll
            for (int i = 0; i < 16; ++i) {
                float4 v = wp[i];
                wrA[4*i] = v.x; wrA[4*i+1] = v.y; wrA[4*i+2] = v.z; wrA[4*i+3] = v.w;
            }
            #pragma unroll
            for (int i = 0; i < 16; ++i) {
                float4 v = wp[16 + i];
                wrB[4*i] = v.x; wrB[4*i+1] = v.y; wrB[4*i+2] = v.z; wrB[4*i+3] = v.w;
            }
        }
        float bsum = (w == 0) ? b1s[rowg] : 0.f;
        float c = (w == 0 && lane < 16) ? new_c[512 + base + lane] : 0.f;
        for (int t = 0; t < 256; ++t) {
            const unsigned* xsrc = (w < 4)
                ? (const unsigned*)h0buf + (t + 1) * 512 + koff
                : (const unsigned*)h1buf + t * 512 + koff;
            unsigned hu0, hu1; int guard = 0;
            for (;;) {
                hu0 = coh_load_u(xsrc + lane);
                hu1 = coh_load_u(xsrc + 64 + lane);
                if (!__any((hu0 == CANARY) || (hu1 == CANARY))) break;
                if (++guard > SPIN_MAX) break;
                if (guard > 32) __builtin_amdgcn_s_sleep(1);
            }
            float hv0 = __uint_as_float(hu0), hv1 = __uint_as_float(hu1);
            float acc = 0.f;
            #pragma unroll
            for (int j = 0; j < 64; ++j)
                acc = fmaf(wrA[j], __shfl(hv0, j), acc);
            #pragma unroll
            for (int j = 0; j < 64; ++j)
                acc = fmaf(wrB[j], __shfl(hv1, j), acc);
            partial[t & 1][w][lane] = acc;
            __syncthreads();
            if (w == 0) {
                float g = bsum;
                #pragma unroll
                for (int ww = 0; ww < 8; ++ww) g += partial[t & 1][ww][lane];
                float a = (gate == 2) ? tanhf(g) : 1.f / (1.f + expf(-g));
                float fv = __shfl(a, lane + 16);
                float gv = __shfl(a, lane + 32);
                float ov = __shfl(a, lane + 48);
                if (lane < 16) {
                    c = fv * c + a * gv;
                    float h = ov * tanhf(c);
                    coh_store_f(h1buf + (t + 1) * 512 + base + lane, h);
                }
            }
        }
    }
}

// ---------------------------------------------------------------------------
extern "C" void kernel_launch(void* const* d_in, const int* in_sizes, int n_in,
                              void* d_out, int out_size, void* d_ws, size_t ws_size,
                              hipStream_t stream)
{
    const float* x      = (const float*)d_in[0];
    const int*   ei     = (const int*)d_in[1];
    const float* h0     = (const float*)d_in[4];
    const float* c0     = (const float*)d_in[5];
    const float* W_gnn  = (const float*)d_in[6];
    const float* W_root = (const float*)d_in[7];
    const float* W_nbr  = (const float*)d_in[8];
    const float* b_conv = (const float*)d_in[9];
    const float* W1     = (const float*)d_in[10];
    const float* b1     = (const float*)d_in[11];
    const float* gamma  = (const float*)d_in[12];
    const float* beta   = (const float*)d_in[13];
    const float* W2     = (const float*)d_in[14];
    const float* b2     = (const float*)d_in[15];
    const float* W_alm  = (const float*)d_in[16];
    const float* b_alm  = (const float*)d_in[17];
    const float* Wih0   = (const float*)d_in[18];
    const float* Whh0   = (const float*)d_in[19];
    const float* bih0   = (const float*)d_in[20];
    const float* bhh0   = (const float*)d_in[21];
    const float* Wih1   = (const float*)d_in[22];
    const float* Whh1   = (const float*)d_in[23];
    const float* bih1   = (const float*)d_in[24];
    const float* bhh1   = (const float*)d_in[25];
    const float* W_fc   = (const float*)d_in[26];
    const float* b_fc   = (const float*)d_in[27];
    float* out = (float*)d_out;
    float* ws  = (float*)d_ws;

    const int* ei0 = ei;
    const int* ei1 = ei + E_EDGE;

    // ---- workspace layout (floats) ----
    float* xr = ws;                       // 25600x256
    float* xn = ws + 6553600L;            // 25600x256
    float* xc = ws + 13107200L;           // 25600x512 (long-lived)
    float* h1m = ws;                      // 25600x512 overlay (xr+xn dead)
    // overlays in region A (h1m dead after pool):
    unsigned short* Wfct  = (unsigned short*)ws;                  // 32000x512 bf16
    unsigned short* Walmb = (unsigned short*)(ws + 8500000L);     // 100x51200 bf16
    unsigned short* ob    = (unsigned short*)(ws + 11200000L);    // 256x512 bf16
    long o = 26214400L;
    float* Wgr   = ws + o; o += 32768;
    float* Wgn   = ws + o; o += 32768;
    int*   counts= (int*)(ws + o); o += 25600;
    int*   rowptr= (int*)(ws + o); o += 25601;
    int*   cursor= (int*)(ws + o); o += 25600;
    int*   sorted= (int*)(ws + o); o += 409600;
    float* colsum= ws + o; o += 512;
    float* colsq = ws + o; o += 512;
    float* scalev= ws + o; o += 512;
    float* shiftv= ws + o; o += 512;
    float* P     = ws + o; o += 131072;
    float* x_g   = ws + o; o += 131072;
    float* hW    = ws + o; o += 25600;
    float* sW    = ws + o; o += 200;
    float* alphav= ws + o; o += 51200;
    float* newc  = ws + o; o += 1024;
    float* b0s   = ws + o; o += 2048;
    float* b1s   = ws + o; o += 2048;
    float* inp0  = ws + o; o += 524288;
    float* h0st  = ws + o; o += 131584;
    float* h1st  = ws + o; o += 131584;
    unsigned short* xcb = (unsigned short*)(ws + o); o += 3276800;  // 25600x512 bf16

    // 1. fold W_gnn into conv weights
    gemm_tile<false><<<dim3(4, 2, 1), 256, 0, stream>>>(W_gnn, W_root, Wgr, nullptr,
        128, 256, 256, 256, 256, 256, 256);
    gemm_tile<false><<<dim3(4, 2, 1), 256, 0, stream>>>(W_gnn, W_nbr, Wgn, nullptr,
        128, 256, 256, 256, 256, 256, 256);
    // 2. xr = x@Wgr + b_conv ; xn = x@Wgn   (f32: feeds chaos path)
    gemm_tile<false><<<dim3(4, 400, 1), 256, 0, stream>>>(x, Wgr, xr, b_conv,
        N_NODES, 256, 128, 128, 256, 256, 128);
    gemm_tile<false><<<dim3(4, 400, 1), 256, 0, stream>>>(x, Wgn, xn, nullptr,
        N_NODES, 256, 128, 128, 256, 256, 128);
    // 3. forward conv
    zero_i32<<<dim3(100), 256, 0, stream>>>(counts, 25600);
    hist_kernel<<<dim3(1600), 256, 0, stream>>>(ei1, counts, E_EDGE);
    scan_kernel<<<dim3(1), 256, 0, stream>>>(counts, rowptr, cursor, 25600);
    scatter_kernel<<<dim3(1600), 256, 0, stream>>>(ei1, ei0, cursor, sorted, E_EDGE);
    agg_conv_kernel<<<dim3(25600), 256, 0, stream>>>(xr, xn, rowptr, sorted, xc, 0);
    // 4. backward conv
    zero_i32<<<dim3(100), 256, 0, stream>>>(counts, 25600);
    hist_kernel<<<dim3(1600), 256, 0, stream>>>(ei0, counts, E_EDGE);
    scan_kernel<<<dim3(1), 256, 0, stream>>>(counts, rowptr, cursor, 25600);
    scatter_kernel<<<dim3(1600), 256, 0, stream>>>(ei0, ei1, cursor, sorted, E_EDGE);
    agg_conv_kernel<<<dim3(25600), 256, 0, stream>>>(xr, xn, rowptr, sorted, xc, 256);
    // 5. h1 = xc@W1 + b1  (f32: feeds x_g -> inp0 -> chaotic LSTM)
    gemm_tile<false><<<dim3(8, 400, 1), 256, 0, stream>>>(xc, W1, h1m, b1,
        N_NODES, 512, 512, 512, 512, 512, 512);
    // 6. per-column layernorm + relu
    zero_f32<<<dim3(4), 256, 0, stream>>>(colsum, 1024);
    colstat_kernel<<<dim3(200), 512, 0, stream>>>(h1m, colsum, colsq);
    finalize_stats<<<dim3(1), 512, 0, stream>>>(colsum, colsq, gamma, beta, scalev, shiftv);
    norm_relu<<<dim3(2048), 256, 0, stream>>>(h1m, scalev, shiftv, (long)N_NODES * 512);
    // 7. pool, x_g = P@W2 + b2 (f32)
    pool_kernel<<<dim3(256), 512, 0, stream>>>(h1m, P);
    gemm_tile<false><<<dim3(8, 4, 1), 256, 0, stream>>>(P, W2, x_g, b2,
        256, 512, 512, 512, 512, 512, 512);
    // h1m region dead from here: cast overlays for the chaos-safe mfma GEMMs
    transcast<<<dim3(500, 8), 256, 0, stream>>>(W_fc, Wfct, 512, V_OUT);
    cast_strided<<<dim3(50, 100), 256, 0, stream>>>(W_alm, Walmb, 51200, 51712L, 512L);
    castbf<<<dim3(1024), 256, 0, stream>>>(xc, xcb, 13107200L);
    // 8. hW = xc_flat(256x51200) @ Wh^T -- bf16 MFMA split-K (chaos-safe)
    zero_f32<<<dim3(25), 256, 0, stream>>>(hW, 25600);
    mfma_gemm<<<dim3(1, 2, 32), 256, 0, stream>>>(xcb, Walmb, hW, nullptr,
        256, 100, 51200, 51200, 51200, 100, 1600);
    // 9. alpha and new_c (f32)
    sw_kernel<<<dim3(1), 256, 0, stream>>>(c0, W_alm, sW);
    alpha_kernel<<<dim3(512), 128, 0, stream>>>(sW, hW, b_alm, alphav);
    zero_f32<<<dim3(1), 256, 0, stream>>>(newc, 1024);
    newc_kernel<<<dim3(32, 2), 512, 0, stream>>>(alphav, xc, newc);
    // 10. LSTM input projection + bias sums (f32: chaos path)
    addvec_kernel<<<dim3(8), 256, 0, stream>>>(bih0, bhh0, b0s, 2048);
    addvec_kernel<<<dim3(8), 256, 0, stream>>>(bih1, bhh1, b1s, 2048);
    gemm_tile<true><<<dim3(32, 4, 1), 256, 0, stream>>>(x_g, Wih0, inp0, b0s,
        256, 2048, 512, 512, 512, 2048, 512);
    // 11. persistent 2-layer LSTM (precise libm)
    lstm_init_kernel<<<dim3(64), 512, 0, stream>>>(h0, h0st, h1st);
    lstm_kernel<<<dim3(64), 512, 0, stream>>>(inp0, Whh0, Wih1, Whh1, b1s, newc,
                                              h0st, h1st);
    // 12. preds = outs1 @ W_fc + b_fc -- bf16 MFMA (leaf, chaos-safe)
    castbf<<<dim3(128), 256, 0, stream>>>(h1st + 512, ob, 131072L);
    mfma_gemm<<<dim3(250, 2, 1), 256, 0, stream>>>(ob, Wfct, out, b_fc,
        256, V_OUT, 512, 512, 512, V_OUT, 512);
}

// Round 7
// 1868.453 us; speedup vs baseline: 2.2816x; 1.1805x over previous
//
#include <hip/hip_runtime.h>
#include <math.h>

#define N_NODES 25600
#define F_IN    128
#define H_GNN   256
#define D_MLP   512
#define E_EDGE  409600
#define B_GR    256
#define NPG_    100
#define R_LSTM  512
#define V_OUT   32000

typedef __bf16 bf16x8 __attribute__((ext_vector_type(8)));
typedef float  f32x4  __attribute__((ext_vector_type(4)));
typedef unsigned short u16x8 __attribute__((ext_vector_type(8)));

__device__ __forceinline__ unsigned short f2bf(float x) {
    unsigned u = __builtin_bit_cast(unsigned, x);
    unsigned r = (u + 0x7FFFu + ((u >> 16) & 1u)) >> 16;
    return (unsigned short)r;
}

// ---------------------------------------------------------------------------
// Generic f32 tiled GEMM — small GEMMs (weight folds, W2, inp0).
// ---------------------------------------------------------------------------
template<bool TRANSB>
__global__ __launch_bounds__(256)
void gemm_tile(const float* __restrict__ A, const float* __restrict__ B,
               float* __restrict__ C, const float* __restrict__ bias,
               int M, int N, int K, int lda, int ldb, int ldc, int kChunk)
{
    __shared__ float As[16][68];
    __shared__ float Bs[16][68];
    const int tid = threadIdx.x;
    const int n0 = blockIdx.x * 64;
    const int m0 = blockIdx.y * 64;
    const int z  = blockIdx.z;
    const int k0 = z * kChunk;
    const int k1 = min(K, k0 + kChunk);
    const int ty = tid >> 4, tx = tid & 15;
    float acc[4][4] = {};

    for (int kb = k0; kb < k1; kb += 16) {
        {
            const int r = tid >> 4, c = tid & 15;
            #pragma unroll
            for (int i = 0; i < 4; ++i) {
                int rr = r + i * 16;
                int gm = m0 + rr, gk = kb + c;
                As[c][rr] = (gm < M && gk < k1) ? A[gm * lda + gk] : 0.f;
            }
        }
        if (!TRANSB) {
            const int r = tid >> 6, c = tid & 63;
            #pragma unroll
            for (int i = 0; i < 4; ++i) {
                int rr = r + i * 4;
                int gk = kb + rr, gn = n0 + c;
                Bs[rr][c] = (gk < k1 && gn < N) ? B[gk * ldb + gn] : 0.f;
            }
        } else {
            const int r = tid & 15, c = tid >> 4;
            #pragma unroll
            for (int i = 0; i < 4; ++i) {
                int cc = c + i * 16;
                int gk = kb + r, gn = n0 + cc;
                Bs[r][cc] = (gk < k1 && gn < N) ? B[gn * ldb + gk] : 0.f;
            }
        }
        __syncthreads();
        #pragma unroll
        for (int kk = 0; kk < 16; ++kk) {
            float a[4], b[4];
            #pragma unroll
            for (int i = 0; i < 4; ++i) a[i] = As[kk][ty * 4 + i];
            #pragma unroll
            for (int j = 0; j < 4; ++j) b[j] = Bs[kk][tx * 4 + j];
            #pragma unroll
            for (int i = 0; i < 4; ++i)
                #pragma unroll
                for (int j = 0; j < 4; ++j)
                    acc[i][j] = fmaf(a[i], b[j], acc[i][j]);
        }
        __syncthreads();
    }

    const bool split = (gridDim.z > 1);
    #pragma unroll
    for (int i = 0; i < 4; ++i) {
        int gm = m0 + ty * 4 + i;
        if (gm >= M) continue;
        #pragma unroll
        for (int j = 0; j < 4; ++j) {
            int gn = n0 + tx * 4 + j;
            if (gn >= N) continue;
            float v = acc[i][j];
            if (bias != nullptr && z == 0) v += bias[gn];
            if (split) atomicAdd(&C[gm * ldc + gn], v);
            else       C[gm * ldc + gn] = v;
        }
    }
}

// ---------------------------------------------------------------------------
// Big-tile f32 GEMM: C[M,N] = A[M,K] @ B[K,N] + bias.
// 128x128 tile, 256 threads, 8x8 per-thread micro-tile, K-step 8.
// Requires M%128==0, N%128==0, K%8==0. Exact f32 (k-sequential accumulate).
// ---------------------------------------------------------------------------
__global__ __launch_bounds__(256)
void gemm_f32_big(const float* __restrict__ A, const float* __restrict__ B,
                  float* __restrict__ C, const float* __restrict__ bias,
                  int M, int N, int K, int lda, int ldb, int ldc)
{
    __shared__ float As[8][128];
    __shared__ float Bs[8][128];
    const int tid = threadIdx.x;
    const int tx = tid & 15, ty = tid >> 4;
    const int n0 = blockIdx.x * 128, m0 = blockIdx.y * 128;
    float acc[8][8] = {};

    for (int kb = 0; kb < K; kb += 8) {
        {   // A tile: 128 rows x 8 k. thread t: row t>>1, k-cols (t&1)*4..+4
            int r = tid >> 1, c = (tid & 1) * 4;
            float4 v = *(const float4*)(A + (long)(m0 + r) * lda + kb + c);
            As[c + 0][r] = v.x; As[c + 1][r] = v.y;
            As[c + 2][r] = v.z; As[c + 3][r] = v.w;
        }
        {   // B tile: 8 k x 128 cols. thread t: k-row t>>5, cols (t&31)*4
            int r = tid >> 5, c = (tid & 31) * 4;
            *(float4*)&Bs[r][c] = *(const float4*)(B + (long)(kb + r) * ldb + n0 + c);
        }
        __syncthreads();
        #pragma unroll
        for (int kk = 0; kk < 8; ++kk) {
            float a[8], b[8];
            *(float4*)&a[0] = *(const float4*)&As[kk][ty * 8];
            *(float4*)&a[4] = *(const float4*)&As[kk][ty * 8 + 4];
            *(float4*)&b[0] = *(const float4*)&Bs[kk][tx * 8];
            *(float4*)&b[4] = *(const float4*)&Bs[kk][tx * 8 + 4];
            #pragma unroll
            for (int i = 0; i < 8; ++i)
                #pragma unroll
                for (int j = 0; j < 8; ++j)
                    acc[i][j] = fmaf(a[i], b[j], acc[i][j]);
        }
        __syncthreads();
    }

    #pragma unroll
    for (int i = 0; i < 8; ++i) {
        int gm = m0 + ty * 8 + i;
        #pragma unroll
        for (int j = 0; j < 8; j += 4) {
            int gn = n0 + tx * 8 + j;
            float4 v = {acc[i][j], acc[i][j+1], acc[i][j+2], acc[i][j+3]};
            if (bias != nullptr) {
                v.x += bias[gn]; v.y += bias[gn + 1];
                v.z += bias[gn + 2]; v.w += bias[gn + 3];
            }
            *(float4*)(C + (long)gm * ldc + gn) = v;
        }
    }
}

// ---------------------------------------------------------------------------
// bf16 MFMA GEMM (plain): chaos-safe GEMMs only (hW, preds).
// ---------------------------------------------------------------------------
__global__ __launch_bounds__(256)
void mfma_gemm(const unsigned short* __restrict__ A,
               const unsigned short* __restrict__ Bt,
               float* __restrict__ C, const float* __restrict__ bias,
               int M, int N, int K, int lda, int ldb, int ldc, int kChunk)
{
    __shared__ unsigned short As[128][40];
    __shared__ unsigned short Bs[128][40];
    const int tid  = threadIdx.x;
    const int lane = tid & 63;
    const int wv   = tid >> 6;
    const int wr   = wv >> 1, wc = wv & 1;
    const int n0 = blockIdx.x * 128;
    const int m0 = blockIdx.y * 128;
    const int z  = blockIdx.z;
    const int k0 = z * kChunk;
    const int k1 = min(K, k0 + kChunk);

    const int srow = tid >> 2;
    const int skoff = (tid & 3) * 8;

    f32x4 acc[4][4] = {};

    for (int kb = k0; kb < k1; kb += 32) {
        #pragma unroll
        for (int p = 0; p < 2; ++p) {
            int row = p * 64 + srow;
            u16x8 va = *(const u16x8*)(A + (long)(m0 + row) * lda + kb + skoff);
            *(u16x8*)&As[row][skoff] = va;
            int gb = n0 + row;
            u16x8 vb = {0, 0, 0, 0, 0, 0, 0, 0};
            if (gb < N) vb = *(const u16x8*)(Bt + (long)gb * ldb + kb + skoff);
            *(u16x8*)&Bs[row][skoff] = vb;
        }
        __syncthreads();
        bf16x8 af[4], bfr[4];
        #pragma unroll
        for (int fm = 0; fm < 4; ++fm)
            af[fm] = *(const bf16x8*)&As[wr * 64 + fm * 16 + (lane & 15)][(lane >> 4) * 8];
        #pragma unroll
        for (int fn = 0; fn < 4; ++fn)
            bfr[fn] = *(const bf16x8*)&Bs[wc * 64 + fn * 16 + (lane & 15)][(lane >> 4) * 8];
        #pragma unroll
        for (int fm = 0; fm < 4; ++fm)
            #pragma unroll
            for (int fn = 0; fn < 4; ++fn)
                acc[fm][fn] = __builtin_amdgcn_mfma_f32_16x16x32_bf16(
                    af[fm], bfr[fn], acc[fm][fn], 0, 0, 0);
        __syncthreads();
    }

    const bool split = (gridDim.z > 1);
    #pragma unroll
    for (int fm = 0; fm < 4; ++fm) {
        int row = m0 + wr * 64 + fm * 16 + ((lane >> 4) << 2);
        #pragma unroll
        for (int fn = 0; fn < 4; ++fn) {
            int col = n0 + wc * 64 + fn * 16 + (lane & 15);
            if (col >= N) continue;
            f32x4 v = acc[fm][fn];
            #pragma unroll
            for (int r = 0; r < 4; ++r) {
                float o = v[r];
                if (bias != nullptr && z == 0) o += bias[col];
                if (split) atomicAdd(&C[(long)(row + r) * ldc + col], o);
                else       C[(long)(row + r) * ldc + col] = o;
            }
        }
    }
}

// ---------------------------------------------------------------------------
// cast / transpose kernels
// ---------------------------------------------------------------------------
__global__ void castbf(const float* __restrict__ in, unsigned short* __restrict__ out,
                       long n) {
    long stride = (long)gridDim.x * blockDim.x * 4;
    for (long j = ((long)blockIdx.x * blockDim.x + threadIdx.x) * 4; j < n; j += stride) {
        float4 v = *(const float4*)(in + j);
        ushort4 o;
        o.x = f2bf(v.x); o.y = f2bf(v.y); o.z = f2bf(v.z); o.w = f2bf(v.w);
        *(ushort4*)(out + j) = o;
    }
}
__global__ void cast_strided(const float* __restrict__ in, unsigned short* __restrict__ out,
                             int cols, long ldin, long off) {
    const int r = blockIdx.y;
    int c = (blockIdx.x * blockDim.x + threadIdx.x) * 4;
    if (c < cols) {
        float4 v = *(const float4*)(in + (long)r * ldin + off + c);
        ushort4 o;
        o.x = f2bf(v.x); o.y = f2bf(v.y); o.z = f2bf(v.z); o.w = f2bf(v.w);
        *(ushort4*)(out + (long)r * cols + c) = o;
    }
}
__global__ __launch_bounds__(256)
void transcast(const float* __restrict__ in, unsigned short* __restrict__ out,
               int R, int C) {
    __shared__ unsigned short t[64][72];
    const int c0 = blockIdx.x * 64, r0 = blockIdx.y * 64;
    const int tid = threadIdx.x;
    const int rr = tid >> 2, cg = (tid & 3) * 16;
    #pragma unroll
    for (int i = 0; i < 4; ++i) {
        float4 v = *(const float4*)(in + (long)(r0 + rr) * C + c0 + cg + i * 4);
        t[cg + i * 4 + 0][rr] = f2bf(v.x);
        t[cg + i * 4 + 1][rr] = f2bf(v.y);
        t[cg + i * 4 + 2][rr] = f2bf(v.z);
        t[cg + i * 4 + 3][rr] = f2bf(v.w);
    }
    __syncthreads();
    const int cc = tid >> 2, kg = (tid & 3) * 16;
    #pragma unroll
    for (int i = 0; i < 2; ++i) {
        u16x8 v = *(const u16x8*)&t[cc][kg + i * 8];
        *(u16x8*)(out + (long)(c0 + cc) * R + r0 + kg + i * 8) = v;
    }
}

// ---------------------------------------------------------------------------
// small utility kernels
// ---------------------------------------------------------------------------
__global__ void zero_f32(float* p, long n) {
    for (long i = (long)blockIdx.x * blockDim.x + threadIdx.x; i < n;
         i += (long)gridDim.x * blockDim.x) p[i] = 0.f;
}
__global__ void zero_i32(int* p, long n) {
    for (long i = (long)blockIdx.x * blockDim.x + threadIdx.x; i < n;
         i += (long)gridDim.x * blockDim.x) p[i] = 0;
}
__global__ void addvec_kernel(const float* a, const float* b, float* o, int n) {
    int i = blockIdx.x * blockDim.x + threadIdx.x;
    if (i < n) o[i] = a[i] + b[i];
}
__global__ void concat_bias(const float* __restrict__ b_conv, float* bc2) {
    int i = blockIdx.x * blockDim.x + threadIdx.x;
    if (i < 512) bc2[i] = (i < 256) ? b_conv[i] : 0.f;
}

// CSR build
__global__ void hist_kernel(const int* __restrict__ key, int* counts, int E) {
    int i = blockIdx.x * blockDim.x + threadIdx.x;
    if (i < E) atomicAdd(&counts[key[i]], 1);
}
// hierarchical scan
__global__ __launch_bounds__(256)
void scan_chunk(const int* __restrict__ counts, int* __restrict__ rowptr,
                int* __restrict__ tops, int n) {
    __shared__ int buf[256];
    const int tid = threadIdx.x;
    int i = blockIdx.x * 256 + tid;
    int v = (i < n) ? counts[i] : 0;
    buf[tid] = v;
    __syncthreads();
    for (int off = 1; off < 256; off <<= 1) {
        int add = (tid >= off) ? buf[tid - off] : 0;
        __syncthreads();
        buf[tid] += add;
        __syncthreads();
    }
    if (i < n) rowptr[i + 1] = buf[tid];
    if (tid == 255) tops[blockIdx.x] = buf[255];
}
__global__ __launch_bounds__(128)
void scan_tops(int* tops, int nt) {
    __shared__ int b[128];
    int tid = threadIdx.x;
    int v = (tid < nt) ? tops[tid] : 0;
    b[tid] = v;
    __syncthreads();
    for (int off = 1; off < 128; off <<= 1) {
        int add = (tid >= off) ? b[tid - off] : 0;
        __syncthreads();
        b[tid] += add;
        __syncthreads();
    }
    if (tid < nt) tops[tid] = b[tid] - v;   // exclusive offsets
}
__global__ void scan_fixup(const int* __restrict__ counts, int* __restrict__ rowptr,
                           int* __restrict__ cursor, const int* __restrict__ tops, int n) {
    int i = blockIdx.x * blockDim.x + threadIdx.x;
    if (i < n) {
        int r = rowptr[i + 1] + tops[i >> 8];
        rowptr[i + 1] = r;
        cursor[i] = r - counts[i];
        if (i == 0) rowptr[0] = 0;
    }
}
__global__ void scatter_kernel(const int* __restrict__ key, const int* __restrict__ val,
                               int* cursor, int* sorted, int E) {
    int i = blockIdx.x * blockDim.x + threadIdx.x;
    if (i < E) {
        int pos = atomicAdd(&cursor[key[i]], 1);
        sorted[pos] = val[i];
    }
}
// aggregation + conv epilogue. xrn: [n][0:256]=root(+bias), [n][256:512]=nbr.
__global__ __launch_bounds__(256)
void agg_conv_kernel(const float* __restrict__ xrn,
                     const int* __restrict__ rowptr, const int* __restrict__ sorted,
                     float* __restrict__ xc, int outOff) {
    const int n = blockIdx.x, tid = threadIdx.x;
    float acc = xrn[(long)n * 512 + tid];
    const int s = rowptr[n], e = rowptr[n + 1];
    for (int t = s; t < e; ++t)
        acc += xrn[(long)sorted[t] * 512 + 256 + tid];
    xc[(long)n * 512 + outOff + tid] = fmaxf(acc, 0.f);
}

__global__ __launch_bounds__(512)
void colstat_kernel(const float* __restrict__ h1, float* colsum, float* colsq) {
    const int c = threadIdx.x;
    const int r0 = blockIdx.x * 128;
    float s = 0.f, s2 = 0.f;
    for (int r = 0; r < 128; ++r) {
        float v = h1[(long)(r0 + r) * D_MLP + c];
        s += v; s2 += v * v;
    }
    atomicAdd(&colsum[c], s);
    atomicAdd(&colsq[c], s2);
}
__global__ void finalize_stats(const float* colsum, const float* colsq,
                               const float* gamma, const float* beta,
                               float* scalev, float* shiftv) {
    int c = threadIdx.x;
    float m  = colsum[c] * (1.f / N_NODES);
    float vr = colsq[c] * (1.f / N_NODES) - m * m;
    float g  = gamma[c] * rsqrtf(vr + 1e-5f);
    scalev[c] = g;
    shiftv[c] = beta[c] - m * g;
}
__global__ void norm_relu(float* h, const float* __restrict__ sc,
                          const float* __restrict__ sh, long n) {
    for (long i = (long)blockIdx.x * blockDim.x + threadIdx.x; i < n;
         i += (long)gridDim.x * blockDim.x) {
        int c = (int)(i & 511);
        h[i] = fmaxf(fmaf(h[i], sc[c], sh[c]), 0.f);
    }
}
__global__ __launch_bounds__(512)
void pool_kernel(const float* __restrict__ hrelu, float* P) {
    const int b = blockIdx.x, c = threadIdx.x;
    float s = 0.f;
    for (int i = 0; i < NPG_; ++i) s += hrelu[(long)(b * NPG_ + i) * D_MLP + c];
    P[b * D_MLP + c] = s * (1.f / NPG_);
}
__global__ void sw_kernel(const float* __restrict__ c0, const float* __restrict__ W_alm,
                          float* sW) {
    int i = blockIdx.x * blockDim.x + threadIdx.x;
    if (i < 2 * NPG_) {
        int l = i / NPG_, p = i % NPG_;
        float s = 0.f;
        for (int k = 0; k < R_LSTM; ++k) s += c0[l * R_LSTM + k] * W_alm[p * 51712 + k];
        sW[l * NPG_ + p] = s;
    }
}
__global__ __launch_bounds__(128)
void alpha_kernel(const float* __restrict__ sW, const float* __restrict__ hW,
                  const float* __restrict__ b_alm, float* __restrict__ alpha) {
    const int lb = blockIdx.x;
    const int l = lb >> 8, b = lb & 255;
    const int p = threadIdx.x;
    __shared__ float red[128];
    float v = 0.f;
    if (p < NPG_) v = sW[l * NPG_ + p] + hW[b * NPG_ + p] + b_alm[p];
    red[p] = v;
    __syncthreads();
    for (int s = 64; s > 0; s >>= 1) {
        if (p < s) red[p] += red[p + s];
        __syncthreads();
    }
    float inv = 1.f / red[0];
    if (p < NPG_) alpha[lb * NPG_ + p] = v * inv;
}
__global__ __launch_bounds__(512)
void newc_kernel(const float* __restrict__ alpha, const float* __restrict__ xc,
                 float* new_c) {
    const int l = blockIdx.y, chunk = blockIdx.x, c = threadIdx.x;
    const int r0 = chunk * 800;
    float acc = 0.f;
    for (int r = r0; r < r0 + 800; ++r)
        acc += alpha[l * N_NODES + r] * xc[(long)r * D_MLP + c];
    atomicAdd(&new_c[l * D_MLP + c], acc);
}

// ---------------------------------------------------------------------------
// Persistent 2-layer LSTM, canary sync, precise libm transcendentals.
// (Chaos path: exact f32 only.)
// ---------------------------------------------------------------------------
#define CANARY 0x7FC00000u
#define SPIN_MAX 20000

__device__ __forceinline__ unsigned coh_load_u(const unsigned* p) {
    return __hip_atomic_load(p, __ATOMIC_RELAXED, __HIP_MEMORY_SCOPE_AGENT);
}
__device__ __forceinline__ void coh_store_f(float* p, float v) {
    __hip_atomic_store(p, v, __ATOMIC_RELAXED, __HIP_MEMORY_SCOPE_AGENT);
}

__global__ void lstm_init_kernel(const float* __restrict__ h0,
                                 float* h0buf, float* h1buf) {
    int i = blockIdx.x * blockDim.x + threadIdx.x;
    if (i < 512) { h0buf[i] = h0[i]; h1buf[i] = h0[512 + i]; }
    for (int j = 512 + i; j < 257 * 512; j += gridDim.x * blockDim.x) {
        ((unsigned*)h0buf)[j] = CANARY;
        ((unsigned*)h1buf)[j] = CANARY;
    }
}

__global__ __launch_bounds__(512)
void lstm_kernel(const float* __restrict__ inp0, const float* __restrict__ Whh0,
                 const float* __restrict__ Wih1, const float* __restrict__ Whh1,
                 const float* __restrict__ b1s, const float* __restrict__ new_c,
                 float* h0buf, float* h1buf)
{
    const int tid  = threadIdx.x;
    const int lane = tid & 63;
    const int w    = tid >> 6;
    const int blk  = blockIdx.x;
    const int layer = blk >> 5;
    const int base  = (blk & 31) * 16;
    const int gate  = lane >> 4;
    const int hid   = lane & 15;
    const int rowg  = gate * 512 + base + hid;

    __shared__ float partial[2][8][64];

    if (layer == 0) {
        float wr[64];
        {
            const float4* wp = (const float4*)(Whh0 + (long)rowg * 512 + w * 64);
            #pragma unroll
            for (int i = 0; i < 16; ++i) {
                float4 v = wp[i];
                wr[4*i] = v.x; wr[4*i+1] = v.y; wr[4*i+2] = v.z; wr[4*i+3] = v.w;
            }
        }
        float c = (w == 0 && lane < 16) ? new_c[base + lane] : 0.f;
        const unsigned* src_u = (const unsigned*)h0buf + w * 64 + lane;
        for (int t = 0; t < 256; ++t) {
            float ipv = (w == 0) ? inp0[t * 2048 + rowg] : 0.f;
            unsigned hu; int guard = 0;
            for (;;) {
                hu = coh_load_u(src_u + t * 512);
                if (!__any(hu == CANARY)) break;
                if (++guard > SPIN_MAX) break;
                if (guard > 32) __builtin_amdgcn_s_sleep(1);
            }
            float hv = __uint_as_float(hu);
            float acc = 0.f;
            #pragma unroll
            for (int j = 0; j < 64; ++j)
                acc = fmaf(wr[j], __shfl(hv, j), acc);
            partial[t & 1][w][lane] = acc;
            __syncthreads();
            if (w == 0) {
                float g = ipv;
                #pragma unroll
                for (int ww = 0; ww < 8; ++ww) g += partial[t & 1][ww][lane];
                float a = (gate == 2) ? tanhf(g) : 1.f / (1.f + expf(-g));
                float fv = __shfl(a, lane + 16);
                float gv = __shfl(a, lane + 32);
                float ov = __shfl(a, lane + 48);
                if (lane < 16) {
                    c = fv * c + a * gv;
                    float h = ov * tanhf(c);
                    coh_store_f(h0buf + (t + 1) * 512 + base + lane, h);
                }
            }
        }
    } else {
        const float* Wsel = (w < 4) ? Wih1 : Whh1;
        const int koff = (w & 3) * 128;
        float wrA[64], wrB[64];
        {
            const float4* wp = (const float4*)(Wsel + (long)rowg * 512 + koff);
            #pragma unroll
            for (int i = 0; i < 16; ++i) {
                float4 v = wp[i];
                wrA[4*i] = v.x; wrA[4*i+1] = v.y; wrA[4*i+2] = v.z; wrA[4*i+3] = v.w;
            }
            #pragma unroll
            for (int i = 0; i < 16; ++i) {
                float4 v = wp[16 + i];
                wrB[4*i] = v.x; wrB[4*i+1] = v.y; wrB[4*i+2] = v.z; wrB[4*i+3] = v.w;
            }
        }
        float bsum = (w == 0) ? b1s[rowg] : 0.f;
        float c = (w == 0 && lane < 16) ? new_c[512 + base + lane] : 0.f;
        for (int t = 0; t < 256; ++t) {
            const unsigned* xsrc = (w < 4)
                ? (const unsigned*)h0buf + (t + 1) * 512 + koff
                : (const unsigned*)h1buf + t * 512 + koff;
            unsigned hu0, hu1; int guard = 0;
            for (;;) {
                hu0 = coh_load_u(xsrc + lane);
                hu1 = coh_load_u(xsrc + 64 + lane);
                if (!__any((hu0 == CANARY) || (hu1 == CANARY))) break;
                if (++guard > SPIN_MAX) break;
                if (guard > 32) __builtin_amdgcn_s_sleep(1);
            }
            float hv0 = __uint_as_float(hu0), hv1 = __uint_as_float(hu1);
            float acc = 0.f;
            #pragma unroll
            for (int j = 0; j < 64; ++j)
                acc = fmaf(wrA[j], __shfl(hv0, j), acc);
            #pragma unroll
            for (int j = 0; j < 64; ++j)
                acc = fmaf(wrB[j], __shfl(hv1, j), acc);
            partial[t & 1][w][lane] = acc;
            __syncthreads();
            if (w == 0) {
                float g = bsum;
                #pragma unroll
                for (int ww = 0; ww < 8; ++ww) g += partial[t & 1][ww][lane];
                float a = (gate == 2) ? tanhf(g) : 1.f / (1.f + expf(-g));
                float fv = __shfl(a, lane + 16);
                float gv = __shfl(a, lane + 32);
                float ov = __shfl(a, lane + 48);
                if (lane < 16) {
                    c = fv * c + a * gv;
                    float h = ov * tanhf(c);
                    coh_store_f(h1buf + (t + 1) * 512 + base + lane, h);
                }
            }
        }
    }
}

// ---------------------------------------------------------------------------
extern "C" void kernel_launch(void* const* d_in, const int* in_sizes, int n_in,
                              void* d_out, int out_size, void* d_ws, size_t ws_size,
                              hipStream_t stream)
{
    const float* x      = (const float*)d_in[0];
    const int*   ei     = (const int*)d_in[1];
    const float* h0     = (const float*)d_in[4];
    const float* c0     = (const float*)d_in[5];
    const float* W_gnn  = (const float*)d_in[6];
    const float* W_root = (const float*)d_in[7];
    const float* W_nbr  = (const float*)d_in[8];
    const float* b_conv = (const float*)d_in[9];
    const float* W1     = (const float*)d_in[10];
    const float* b1     = (const float*)d_in[11];
    const float* gamma  = (const float*)d_in[12];
    const float* beta   = (const float*)d_in[13];
    const float* W2     = (const float*)d_in[14];
    const float* b2     = (const float*)d_in[15];
    const float* W_alm  = (const float*)d_in[16];
    const float* b_alm  = (const float*)d_in[17];
    const float* Wih0   = (const float*)d_in[18];
    const float* Whh0   = (const float*)d_in[19];
    const float* bih0   = (const float*)d_in[20];
    const float* bhh0   = (const float*)d_in[21];
    const float* Wih1   = (const float*)d_in[22];
    const float* Whh1   = (const float*)d_in[23];
    const float* bih1   = (const float*)d_in[24];
    const float* bhh1   = (const float*)d_in[25];
    const float* W_fc   = (const float*)d_in[26];
    const float* b_fc   = (const float*)d_in[27];
    float* out = (float*)d_out;
    float* ws  = (float*)d_ws;

    const int* ei0 = ei;
    const int* ei1 = ei + E_EDGE;

    // ---- workspace layout (float offsets) ----
    // region A [0, 13107200): xrn -> h1m -> (Wfct, Walmb, ob after pool)
    float* xrn = ws;
    float* h1m = ws;
    unsigned short* Wfct  = (unsigned short*)ws;                 // 32000x512 bf16
    unsigned short* Walmb = (unsigned short*)(ws + 8500000L);    // 100x51200 bf16
    unsigned short* ob    = (unsigned short*)(ws + 11200000L);   // 256x512 bf16
    // region B [13107200, 26214400): xc f32 (25600x512, long-lived)
    float* xc = ws + 13107200L;
    // region C smalls
    long o = 26214400L;
    float* Wc    = ws + o; o += 65536;    // 128x512 f32 combined conv weight
    int*   counts= (int*)(ws + o); o += 25600;
    int*   rowptr= (int*)(ws + o); o += 25601;
    int*   cursor= (int*)(ws + o); o += 25600;
    int*   sorted= (int*)(ws + o); o += 409600;
    int*   tops  = (int*)(ws + o); o += 128;
    float* colsum= ws + o; o += 512;
    float* colsq = ws + o; o += 512;
    float* scalev= ws + o; o += 512;
    float* shiftv= ws + o; o += 512;
    float* P     = ws + o; o += 131072;
    float* x_g   = ws + o; o += 131072;
    float* hW    = ws + o; o += 25600;
    float* sW    = ws + o; o += 200;
    float* alphav= ws + o; o += 51200;
    float* newc  = ws + o; o += 1024;
    float* b0s   = ws + o; o += 2048;
    float* b1s   = ws + o; o += 2048;
    float* bc2   = ws + o; o += 512;
    // xcb (25600x512 bf16 = 6553600 float-slots); dead after hW ->
    // inp0 + LSTM h-state overlay the same region.
    unsigned short* xcb = (unsigned short*)(ws + o);
    float* inp0  = ws + o;            // 524288 (overlays xcb, used after hW)
    float* h0st  = ws + o + 524288;   // 131584
    float* h1st  = ws + o + 655872;   // 131584
    o += 6553600;

    // 1. conv weight folding: Wc[:,0:256]=W_gnn@W_root, Wc[:,256:512]=W_gnn@W_nbr
    gemm_tile<false><<<dim3(4, 2, 1), 256, 0, stream>>>(W_gnn, W_root, Wc, nullptr,
        128, 256, 256, 256, 256, 512, 256);
    gemm_tile<false><<<dim3(4, 2, 1), 256, 0, stream>>>(W_gnn, W_nbr, Wc + 256, nullptr,
        128, 256, 256, 256, 256, 512, 256);
    concat_bias<<<dim3(2), 256, 0, stream>>>(b_conv, bc2);
    // 2. fused conv GEMM (f32): xrn = x @ Wc + bc2
    gemm_f32_big<<<dim3(4, 200), 256, 0, stream>>>(x, Wc, xrn, bc2,
        N_NODES, 512, 128, 128, 512, 512);
    // 3. forward conv: CSR by dst
    zero_i32<<<dim3(100), 256, 0, stream>>>(counts, 25600);
    hist_kernel<<<dim3(1600), 256, 0, stream>>>(ei1, counts, E_EDGE);
    scan_chunk<<<dim3(100), 256, 0, stream>>>(counts, rowptr, tops, 25600);
    scan_tops<<<dim3(1), 128, 0, stream>>>(tops, 100);
    scan_fixup<<<dim3(100), 256, 0, stream>>>(counts, rowptr, cursor, tops, 25600);
    scatter_kernel<<<dim3(1600), 256, 0, stream>>>(ei1, ei0, cursor, sorted, E_EDGE);
    agg_conv_kernel<<<dim3(25600), 256, 0, stream>>>(xrn, rowptr, sorted, xc, 0);
    // 4. backward conv: CSR by src
    zero_i32<<<dim3(100), 256, 0, stream>>>(counts, 25600);
    hist_kernel<<<dim3(1600), 256, 0, stream>>>(ei0, counts, E_EDGE);
    scan_chunk<<<dim3(100), 256, 0, stream>>>(counts, rowptr, tops, 25600);
    scan_tops<<<dim3(1), 128, 0, stream>>>(tops, 100);
    scan_fixup<<<dim3(100), 256, 0, stream>>>(counts, rowptr, cursor, tops, 25600);
    scatter_kernel<<<dim3(1600), 256, 0, stream>>>(ei0, ei1, cursor, sorted, E_EDGE);
    agg_conv_kernel<<<dim3(25600), 256, 0, stream>>>(xrn, rowptr, sorted, xc, 256);
    // 5. h1 = xc@W1 + b1 (exact f32, big-tile; xrn dead -> h1m overlays A)
    gemm_f32_big<<<dim3(4, 200), 256, 0, stream>>>(xc, W1, h1m, b1,
        N_NODES, 512, 512, 512, 512, 512);
    // 6. per-column layernorm + relu
    zero_f32<<<dim3(4), 256, 0, stream>>>(colsum, 1024);
    colstat_kernel<<<dim3(200), 512, 0, stream>>>(h1m, colsum, colsq);
    finalize_stats<<<dim3(1), 512, 0, stream>>>(colsum, colsq, gamma, beta, scalev, shiftv);
    norm_relu<<<dim3(2048), 256, 0, stream>>>(h1m, scalev, shiftv, (long)N_NODES * 512);
    // 7. pool, x_g = P@W2 + b2 (f32)
    pool_kernel<<<dim3(256), 512, 0, stream>>>(h1m, P);
    gemm_tile<false><<<dim3(8, 4, 1), 256, 0, stream>>>(P, W2, x_g, b2,
        256, 512, 512, 512, 512, 512, 512);
    // h1m dead: overlay casts for chaos-safe MFMA GEMMs
    transcast<<<dim3(500, 8), 256, 0, stream>>>(W_fc, Wfct, 512, V_OUT);
    cast_strided<<<dim3(50, 100), 256, 0, stream>>>(W_alm, Walmb, 51200, 51712L, 512L);
    castbf<<<dim3(1024), 256, 0, stream>>>(xc, xcb, 13107200L);
    // 8. hW = xc_flat(256x51200) @ Wh^T -- bf16 MFMA split-K (chaos-safe)
    zero_f32<<<dim3(25), 256, 0, stream>>>(hW, 25600);
    mfma_gemm<<<dim3(1, 2, 32), 256, 0, stream>>>(xcb, Walmb, hW, nullptr,
        256, 100, 51200, 51200, 51200, 100, 1600);
    // 9. alpha and new_c (f32 xc)
    sw_kernel<<<dim3(1), 256, 0, stream>>>(c0, W_alm, sW);
    alpha_kernel<<<dim3(512), 128, 0, stream>>>(sW, hW, b_alm, alphav);
    zero_f32<<<dim3(1), 256, 0, stream>>>(newc, 1024);
    newc_kernel<<<dim3(32, 2), 512, 0, stream>>>(alphav, xc, newc);
    // 10. LSTM input projection + bias sums (f32; xcb dead -> inp0 overlays)
    addvec_kernel<<<dim3(8), 256, 0, stream>>>(bih0, bhh0, b0s, 2048);
    addvec_kernel<<<dim3(8), 256, 0, stream>>>(bih1, bhh1, b1s, 2048);
    gemm_tile<true><<<dim3(32, 4, 1), 256, 0, stream>>>(x_g, Wih0, inp0, b0s,
        256, 2048, 512, 512, 512, 2048, 512);
    // 11. persistent 2-layer LSTM
    lstm_init_kernel<<<dim3(64), 512, 0, stream>>>(h0, h0st, h1st);
    lstm_kernel<<<dim3(64), 512, 0, stream>>>(inp0, Whh0, Wih1, Whh1, b1s, newc,
                                              h0st, h1st);
    // 12. preds = outs1 @ W_fc + b_fc -- bf16 MFMA (leaf)
    castbf<<<dim3(128), 256, 0, stream>>>(h1st + 512, ob, 131072L);
    mfma_gemm<<<dim3(250, 2, 1), 256, 0, stream>>>(ob, Wfct, out, b_fc,
        256, V_OUT, 512, 512, 512, V_OUT, 512);
}